// Round 2
// baseline (2140.159 us; speedup 1.0000x reference)
//
#include <hip/hip_runtime.h>
#include <hip/hip_bf16.h>

// GeometricModalityFusion — Round 2: bf16-intermediate fp32-accumulate version.
// Crash theory from R1: ws_size < 339 MB -> OOB fault. New ws budget ~163 MB:
//   feats bf16 (96MB) | kv bf16 (32MB) | fused bf16 (32MB) | scores f32 (3MB) | accum/coef
// projq bf16 (32MB) lives in d_out (dead before final GEMM writes d_out).
//
// Derivations (verified against the JAX reference semantics):
//  * reshape(B,H,S,HD) is a RAW reshape: q[b,h,s,e]=proj[b, h*128+s/8, 64*(s%8)+e]
//    -> per (row R, 64-col block beta): 64-dot, softmax over M=3, blend of V rows,
//       scattered to out row s'=(R%128)*8+beta, cols [64*(R/128),+64).
//  * pad rows of feats are 0 -> K/V/Q pad rows == bias row (fill kernels).
//  * Cayley volumes need only the per-batch 3x3 Gram; angular needs per-position
//    normalized cross-dots summed over s. Both reduce to per-batch coefficients.

constexpr int CB = 32;
constexpr int CS = 1024;
constexpr int CD = 512;
constexpr int CBS = CB * CS;                  // 32768
constexpr size_t CBSD = (size_t)CBS * CD;     // 16,777,216 elements

typedef unsigned short u16;

__device__ __forceinline__ float bf2f(u16 u) {
    return __uint_as_float(((unsigned)u) << 16);
}
__device__ __forceinline__ u16 f2bf(float f) {
    unsigned u = __float_as_uint(f);
    return (u16)((u + 0x7FFFu + ((u >> 16) & 1u)) >> 16);
}

// ---------------------------------------------------------------------------
// GEMM: C[mapOut(r), n] = sum_k A[mapIn(r), k] * W[k, n] + bias[n]
// map(r, lg) = ((r>>lg)<<10) | (r & ((1<<lg)-1));  lg=10 -> identity.
// Tiles 64x128, BK=16, 256 threads, 4x8 per thread. N fixed = 512. W,bias fp32.
// ---------------------------------------------------------------------------
template <bool A_BF16, bool C_BF16>
__global__ __launch_bounds__(256) void gemm_bias(
    const void* __restrict__ Av, const float* __restrict__ W,
    const float* __restrict__ bias, void* __restrict__ Cv,
    int K, int lgIn, int lgOut)
{
    __shared__ float As[16][68];
    __shared__ float Ws[16][128];
    const int row0 = blockIdx.x * 64;
    const int n0 = blockIdx.y * 128;
    const int tid = threadIdx.x;
    const int tx = tid & 15;
    const int ty = tid >> 4;

    const int arow = tid >> 2;              // 0..63
    const int ak = (tid & 3) << 2;          // 0,4,8,12
    const int rIn = row0 + arow;
    const size_t inRow = ((size_t)(rIn >> lgIn) << 10) + (size_t)(rIn & ((1 << lgIn) - 1));

    float acc[4][8];
#pragma unroll
    for (int i = 0; i < 4; ++i)
#pragma unroll
        for (int j = 0; j < 8; ++j) acc[i][j] = 0.0f;

    for (int k0 = 0; k0 < K; k0 += 16) {
        float4 av;
        if constexpr (A_BF16) {
            const u16* A = (const u16*)Av + inRow * (size_t)K + ak;
            ushort4 u = *(const ushort4*)(A + k0);
            av.x = bf2f(u.x); av.y = bf2f(u.y); av.z = bf2f(u.z); av.w = bf2f(u.w);
        } else {
            const float* A = (const float*)Av + inRow * (size_t)K + ak;
            av = *(const float4*)(A + k0);
        }
        As[ak + 0][arow] = av.x;
        As[ak + 1][arow] = av.y;
        As[ak + 2][arow] = av.z;
        As[ak + 3][arow] = av.w;
#pragma unroll
        for (int jj = 0; jj < 2; ++jj) {
            int ii = tid + (jj << 8);
            int wr = ii >> 5;
            int wc = (ii & 31) << 2;
            *(float4*)&Ws[wr][wc] = *(const float4*)(W + (size_t)(k0 + wr) * CD + n0 + wc);
        }
        __syncthreads();
#pragma unroll
        for (int k = 0; k < 16; ++k) {
            const float4 a4 = *(const float4*)&As[k][ty << 2];
            const float4 wa = *(const float4*)&Ws[k][tx << 2];
            const float4 wb = *(const float4*)&Ws[k][64 + (tx << 2)];
            const float aa[4] = {a4.x, a4.y, a4.z, a4.w};
            const float ww[8] = {wa.x, wa.y, wa.z, wa.w, wb.x, wb.y, wb.z, wb.w};
#pragma unroll
            for (int i = 0; i < 4; ++i)
#pragma unroll
                for (int j = 0; j < 8; ++j)
                    acc[i][j] = fmaf(aa[i], ww[j], acc[i][j]);
        }
        __syncthreads();
    }

    const float4 blo = *(const float4*)(bias + n0 + (tx << 2));
    const float4 bhi = *(const float4*)(bias + n0 + 64 + (tx << 2));
#pragma unroll
    for (int i = 0; i < 4; ++i) {
        int r = row0 + (ty << 2) + i;
        size_t outRow = ((size_t)(r >> lgOut) << 10) + (size_t)(r & ((1 << lgOut) - 1));
        float v0 = acc[i][0] + blo.x, v1 = acc[i][1] + blo.y;
        float v2 = acc[i][2] + blo.z, v3 = acc[i][3] + blo.w;
        float v4 = acc[i][4] + bhi.x, v5 = acc[i][5] + bhi.y;
        float v6 = acc[i][6] + bhi.z, v7 = acc[i][7] + bhi.w;
        if constexpr (C_BF16) {
            u16* crow = (u16*)Cv + outRow * CD + n0;
            *(ushort4*)(crow + (tx << 2)) = make_ushort4(f2bf(v0), f2bf(v1), f2bf(v2), f2bf(v3));
            *(ushort4*)(crow + 64 + (tx << 2)) = make_ushort4(f2bf(v4), f2bf(v5), f2bf(v6), f2bf(v7));
        } else {
            float* crow = (float*)Cv + outRow * CD + n0;
            *(float4*)(crow + (tx << 2)) = make_float4(v0, v1, v2, v3);
            *(float4*)(crow + 64 + (tx << 2)) = make_float4(v4, v5, v6, v7);
        }
    }
}

// Fill pad rows [Lstart, S) of a (B,S,D) bf16 buffer with the fp32 bias row.
__global__ void fill_rows_bf16(u16* __restrict__ dst, const float* __restrict__ bias,
                               int Lstart)
{
    int s = Lstart + blockIdx.x;
    int b = blockIdx.y;
    ushort4* r = (ushort4*)(dst + ((size_t)b * CS + s) * CD);
    int c = threadIdx.x;  // 128 threads, 4 elems each
    float4 bv = ((const float4*)bias)[c];
    r[c] = make_ushort4(f2bf(bv.x), f2bf(bv.y), f2bf(bv.z), f2bf(bv.w));
}

// Zero pad rows [Lstart, S) of a (B,S,D) bf16 buffer.
__global__ void zero_rows_bf16(u16* __restrict__ dst, int Lstart)
{
    int s = Lstart + blockIdx.x;
    int b = blockIdx.y;
    ushort4* r = (ushort4*)(dst + ((size_t)b * CS + s) * CD);
    r[threadIdx.x] = make_ushort4(0, 0, 0, 0);
}

// scores[bR*8 + beta] = sum_{e<64} q[bR, 64*beta+e] * k[bR, 64*beta+e]
__global__ __launch_bounds__(256) void scores_kernel(
    const u16* __restrict__ q, const u16* __restrict__ k,
    float* __restrict__ scoresM)
{
    int bR = blockIdx.x * 4 + (threadIdx.x >> 6);
    int lane = threadIdx.x & 63;
    const u16* qp = q + (size_t)bR * CD + lane;
    const u16* kp = k + (size_t)bR * CD + lane;
    float p[8];
#pragma unroll
    for (int i = 0; i < 8; ++i) p[i] = bf2f(qp[i * 64]) * bf2f(kp[i * 64]);
#pragma unroll
    for (int off = 32; off >= 1; off >>= 1) {
#pragma unroll
        for (int i = 0; i < 8; ++i) p[i] += __shfl_xor(p[i], off, 64);
    }
    if (lane == 0) {
        float4* o = (float4*)(scoresM + (size_t)bR * 8);
        o[0] = make_float4(p[0], p[1], p[2], p[3]);
        o[1] = make_float4(p[4], p[5], p[6], p[7]);
    }
}

// Per-batch reductions: 3x3 Gram F and angular cos numerators.
// accum[b*9 + {F00,F11,F22,F01,F02,F12,c01,c02,c12}]
__global__ __launch_bounds__(256) void stats_kernel(
    const u16* __restrict__ feats, float* __restrict__ accum)
{
    int b = blockIdx.x >> 5;
    int chunk = blockIdx.x & 31;
    int wave = threadIdx.x >> 6, lane = threadIdx.x & 63;
    float a0 = 0, a1 = 0, a2 = 0, a3 = 0, a4 = 0, a5 = 0, a6 = 0, a7 = 0, a8 = 0;
    const u16* base = feats + (size_t)b * CS * CD + lane;
    for (int t = 0; t < 8; ++t) {
        int s = (chunk << 5) + (wave << 3) + t;
        const u16* f0 = base + (size_t)s * CD;
        const u16* f1 = f0 + CBSD;
        const u16* f2 = f1 + CBSD;
        float d00 = 0, d11 = 0, d22 = 0, d01 = 0, d02 = 0, d12 = 0;
#pragma unroll
        for (int j = 0; j < 8; ++j) {
            float x0 = bf2f(f0[j * 64]), x1 = bf2f(f1[j * 64]), x2 = bf2f(f2[j * 64]);
            d00 = fmaf(x0, x0, d00); d11 = fmaf(x1, x1, d11); d22 = fmaf(x2, x2, d22);
            d01 = fmaf(x0, x1, d01); d02 = fmaf(x0, x2, d02); d12 = fmaf(x1, x2, d12);
        }
#pragma unroll
        for (int off = 32; off >= 1; off >>= 1) {
            d00 += __shfl_xor(d00, off, 64);
            d11 += __shfl_xor(d11, off, 64);
            d22 += __shfl_xor(d22, off, 64);
            d01 += __shfl_xor(d01, off, 64);
            d02 += __shfl_xor(d02, off, 64);
            d12 += __shfl_xor(d12, off, 64);
        }
        float n0 = fmaxf(sqrtf(d00), 1e-12f);
        float n1 = fmaxf(sqrtf(d11), 1e-12f);
        float n2 = fmaxf(sqrtf(d22), 1e-12f);
        a0 += d00; a1 += d11; a2 += d22; a3 += d01; a4 += d02; a5 += d12;
        a6 += d01 / (n0 * n1); a7 += d02 / (n0 * n2); a8 += d12 / (n1 * n2);
    }
    if (lane == 0) {
        float* acc = accum + b * 9;
        atomicAdd(acc + 0, a0); atomicAdd(acc + 1, a1); atomicAdd(acc + 2, a2);
        atomicAdd(acc + 3, a3); atomicAdd(acc + 4, a4); atomicAdd(acc + 5, a5);
        atomicAdd(acc + 6, a6); atomicAdd(acc + 7, a7); atomicAdd(acc + 8, a8);
    }
}

// coef[0]=1/(8|t|), coef[1]=w0, coef[4+b*3+i] = w1*aw[b,i] + w2*cw[b,i].
__global__ void finalize_kernel(const float* __restrict__ accum,
                                const float* __restrict__ temp,
                                const float* __restrict__ attw,
                                const float* __restrict__ rolew,
                                float* __restrict__ coef)
{
    float t_abs = fabsf(temp[0]);
    float x0 = attw[0], x1 = attw[1], x2 = attw[2];
    float mx = fmaxf(x0, fmaxf(x1, x2));
    float e0 = expf(x0 - mx), e1 = expf(x1 - mx), e2 = expf(x2 - mx);
    float inv = 1.0f / (e0 + e1 + e2);
    float w0 = e0 * inv, w1 = e1 * inv, w2 = e2 * inv;
    int b = threadIdx.x;
    if (b == 0) { coef[0] = 1.0f / (8.0f * t_abs); coef[1] = w0; }
    if (b < CB) {
        const float* A = accum + b * 9;
        float Fm[3][3];
        Fm[0][0] = A[0]; Fm[1][1] = A[1]; Fm[2][2] = A[2];
        Fm[0][1] = Fm[1][0] = A[3];
        Fm[0][2] = Fm[2][0] = A[4];
        Fm[1][2] = Fm[2][1] = A[5];
        float cn[3] = {A[6], A[7], A[8]};   // (0,1) (0,2) (1,2)
        float eij[3];
#pragma unroll
        for (int p = 0; p < 3; ++p) {
            float c = cn[p] * (1.0f / 1024.0f);
            c = fminf(fmaxf(c, -1.0f + 1e-7f), 1.0f - 1e-7f);
            eij[p] = expf(-acosf(c) / t_abs);
        }
        float r0 = rolew[0], r1 = rolew[1], r2 = rolew[2];
        float as0 = r1 * eij[0] + r2 * eij[1];
        float as1 = r0 * eij[0] + r2 * eij[2];
        float as2 = r0 * eij[1] + r1 * eij[2];
        float amx = fmaxf(as0, fmaxf(as1, as2));
        float ea0 = expf(as0 - amx), ea1 = expf(as1 - amx), ea2 = expf(as2 - amx);
        float ainv = 1.0f / (ea0 + ea1 + ea2);
        float awv[3] = {ea0 * ainv, ea1 * ainv, ea2 * ainv};
        const float CA = 0.70710678118654752440f;   // cos(pi/4)
        const float C2 = 6.123233995736766e-17f;    // cos(pi/2)
        float vols[3];
#pragma unroll
        for (int i = 0; i < 3; ++i) {
            int j1 = (i + 1) % 3, j2 = (i + 2) % 3;
            float G00 = Fm[i][i];
            float G11 = CA * CA * (Fm[i][i] + 2.0f * Fm[i][j1] + Fm[j1][j1]);
            float G22 = C2 * C2 * Fm[i][i] + 2.0f * C2 * Fm[i][j2] + Fm[j2][j2];
            float G01 = CA * (Fm[i][i] + Fm[i][j1]);
            float G02 = C2 * Fm[i][i] + Fm[i][j2];
            float G12 = CA * (C2 * (Fm[i][i] + Fm[i][j1]) + Fm[i][j2] + Fm[j1][j2]);
            vols[i] = (4.0f / 9.0f) * ((G00 + G11 + G22) - (G01 + G02 + G12));
        }
        float vmx = fmaxf(vols[0], fmaxf(vols[1], vols[2]));
        float ev0 = expf((vols[0] - vmx) / t_abs);
        float ev1 = expf((vols[1] - vmx) / t_abs);
        float ev2 = expf((vols[2] - vmx) / t_abs);
        float vinv = 1.0f / (ev0 + ev1 + ev2);
        coef[4 + b * 3 + 0] = w1 * awv[0] + w2 * (ev0 * vinv);
        coef[4 + b * 3 + 1] = w1 * awv[1] + w2 * (ev1 * vinv);
        coef[4 + b * 3 + 2] = w1 * awv[2] + w2 * (ev2 * vinv);
    }
}

// fused[b,s',d'] = w0 * attn_m * v_m (accumulated over m-passes)
//                + sum_i g[b,i]*feats[i,b,s',d']   (added on m==0 pass)
__global__ __launch_bounds__(256) void blend_kernel(
    const u16* __restrict__ vbuf, const u16* __restrict__ feats,
    const float* __restrict__ scores, const float* __restrict__ coef,
    u16* __restrict__ fused, int m)
{
    int bR = blockIdx.x;
    int b = bR >> 10, R = bR & 1023;
    float inv_scale = coef[0], w0 = coef[1];
    float g0 = coef[4 + b * 3 + 0];
    float g1 = coef[4 + b * 3 + 1];
    float g2 = coef[4 + b * 3 + 2];
    int h = R >> 7;
    int spBase = (R & 127) << 3;
#pragma unroll
    for (int it = 0; it < 2; ++it) {
        int c = (it << 8) + threadIdx.x;
        int beta = c >> 6, e = c & 63;
        size_t sidx = (size_t)bR * 8 + beta;
        float s0 = scores[sidx] * inv_scale;
        float s1 = scores[(size_t)CBS * 8 + sidx] * inv_scale;
        float s2 = scores[(size_t)2 * CBS * 8 + sidx] * inv_scale;
        float mxs = fmaxf(s0, fmaxf(s1, s2));
        float ex0 = expf(s0 - mxs), ex1 = expf(s1 - mxs), ex2 = expf(s2 - mxs);
        float sel = (m == 0) ? ex0 : ((m == 1) ? ex1 : ex2);
        float attn = sel / (ex0 + ex1 + ex2);
        float v = bf2f(vbuf[(size_t)bR * CD + c]);
        int sp = spBase + beta;
        int dp = (h << 6) + e;
        size_t off = ((size_t)(b << 10) + sp) * CD + dp;
        float val = w0 * attn * v;
        if (m == 0) {
            val += g0 * bf2f(feats[off]) + g1 * bf2f(feats[off + CBSD])
                 + g2 * bf2f(feats[off + 2 * CBSD]);
            fused[off] = f2bf(val);
        } else {
            fused[off] = f2bf(bf2f(fused[off]) + val);
        }
    }
}

extern "C" void kernel_launch(void* const* d_in, const int* in_sizes, int n_in,
                              void* d_out, int out_size, void* d_ws, size_t ws_size,
                              hipStream_t stream)
{
    const float* text  = (const float*)d_in[0];
    const float* image = (const float*)d_in[1];
    const float* audio = (const float*)d_in[2];
    const float* W0 = (const float*)d_in[3];  const float* b0 = (const float*)d_in[4];
    const float* W1 = (const float*)d_in[5];  const float* b1 = (const float*)d_in[6];
    const float* W2 = (const float*)d_in[7];  const float* b2 = (const float*)d_in[8];
    const float* Wq = (const float*)d_in[9];  const float* bq = (const float*)d_in[10];
    const float* Wk = (const float*)d_in[11]; const float* bk = (const float*)d_in[12];
    const float* Wv = (const float*)d_in[13]; const float* bv = (const float*)d_in[14];
    const float* Wo = (const float*)d_in[15]; const float* bo = (const float*)d_in[16];
    const float* temp  = (const float*)d_in[17];
    const float* attw  = (const float*)d_in[18];
    const float* rolew = (const float*)d_in[19];

    // ws layout (bf16 elements unless noted): total ~163.3 MB
    u16* feats  = (u16*)d_ws;                 // 3*CBSD
    u16* kv     = feats + 3 * CBSD;           // CBSD
    u16* fused  = kv + CBSD;                  // CBSD
    float* scores = (float*)(fused + CBSD);   // 3*CBS*8 f32
    float* accum  = scores + (size_t)3 * CBS * 8;  // 288 f32 (reserve 320)
    float* coef   = accum + 320;              // 100 f32
    u16* q = (u16*)d_out;                     // scratch: dead before final GEMM

    const dim3 blk(256);
    const int Lm[3] = {512, 256, 1024};
    const int lg[3] = {9, 8, 10};

    // zero the pad rows of feats (mod2 has none), zero accum for atomics
    zero_rows_bf16<<<dim3(512, CB), dim3(128), 0, stream>>>(feats, 512);
    zero_rows_bf16<<<dim3(768, CB), dim3(128), 0, stream>>>(feats + CBSD, 256);
    hipMemsetAsync(accum, 0, 320 * sizeof(float), stream);

    // input projections -> feats (real rows only; pads are zero)
    gemm_bias<false, true><<<dim3(256, 4), blk, 0, stream>>>(text,  W0, b0, feats,            768, 10,  9);
    gemm_bias<false, true><<<dim3(128, 4), blk, 0, stream>>>(image, W1, b1, feats + CBSD,    1024, 10,  8);
    gemm_bias<false, true><<<dim3(512, 4), blk, 0, stream>>>(audio, W2, b2, feats + 2 * CBSD, 512, 10, 10);

    // Q projection (real rows) + bias fill for pad rows
    gemm_bias<true, true><<<dim3(256, 4), blk, 0, stream>>>(feats, Wq, bq, q, 512, 9, 9);
    fill_rows_bf16<<<dim3(512, CB), dim3(128), 0, stream>>>(q, bq, 512);

    // angular + Cayley stats
    stats_kernel<<<dim3(CB * 32), blk, 0, stream>>>(feats, accum);
    finalize_kernel<<<dim3(1), dim3(64), 0, stream>>>(accum, temp, attw, rolew, coef);

    // K per modality -> scores
    for (int m = 0; m < 3; ++m) {
        gemm_bias<true, true><<<dim3(CB * Lm[m] / 64, 4), blk, 0, stream>>>(
            feats + (size_t)m * CBSD, Wk, bk, kv, 512, lg[m], lg[m]);
        if (Lm[m] < CS)
            fill_rows_bf16<<<dim3(CS - Lm[m], CB), dim3(128), 0, stream>>>(kv, bk, Lm[m]);
        scores_kernel<<<dim3(CBS / 4), blk, 0, stream>>>(q, kv, scores + (size_t)m * CBS * 8);
    }

    // V per modality -> blend into fused (pass 0 also adds angular+cayley terms)
    for (int m = 0; m < 3; ++m) {
        gemm_bias<true, true><<<dim3(CB * Lm[m] / 64, 4), blk, 0, stream>>>(
            feats + (size_t)m * CBSD, Wv, bv, kv, 512, lg[m], lg[m]);
        if (Lm[m] < CS)
            fill_rows_bf16<<<dim3(CS - Lm[m], CB), dim3(128), 0, stream>>>(kv, bv, Lm[m]);
        blend_kernel<<<dim3(CBS), blk, 0, stream>>>(kv, feats, scores, coef, fused, m);
    }

    // output projection (reads fused in ws, writes fp32 d_out; q is dead)
    gemm_bias<true, false><<<dim3(512, 4), blk, 0, stream>>>(fused, Wo, bo, (float*)d_out, 512, 10, 10);
}

// Round 4
// 792.240 us; speedup vs baseline: 2.7014x; 2.7014x over previous
//
#include <hip/hip_runtime.h>
#include <hip/hip_bf16.h>

// GeometricModalityFusion — Round 3/4: all GEMMs -> bf16 MFMA (m97 structure).
// (R3 bench never ran: GPU acquisition timeout. Identical resubmission.)
// 128x128 tile, BK=32, 4 waves, global_load_lds(16B), 16x mfma_16x16x32_bf16
// + 8x ds_read_b128 per K-step, 2-barrier loop. Weights transposed to
// Wt[N][K] bf16 (stored in d_out tail; Wo's in ws to avoid write race).
// Inputs converted fp32->bf16 through the kv staging buffer.
//
// Semantics (unchanged from R2, verified passing):
//  * raw reshape: per (row R, 64-col block beta): 64-dot, softmax over M=3,
//    blend of V rows, scatter to row s'=(R%128)*8+beta, cols [64*(R/128),+64).
//  * pad rows of feats are 0 -> K/V/Q pad rows == bias row.
//  * Cayley needs only per-batch 3x3 Gram; angular needs per-position
//    normalized cross-dots summed over s -> per-batch coefficients.

constexpr int CB = 32;
constexpr int CS = 1024;
constexpr int CD = 512;
constexpr int CBS = CB * CS;                  // 32768
constexpr size_t CBSD = (size_t)CBS * CD;     // 16,777,216 elements

typedef unsigned short u16;
typedef float f32x4 __attribute__((ext_vector_type(4)));
typedef int i32x4 __attribute__((ext_vector_type(4)));

__device__ __forceinline__ float bf2f(u16 u) {
    return __uint_as_float(((unsigned)u) << 16);
}
__device__ __forceinline__ u16 f2bf(float f) {
    unsigned u = __float_as_uint(f);
    return (u16)((u + 0x7FFFu + ((u >> 16) & 1u)) >> 16);
}
__device__ __forceinline__ size_t mapRow(int r, int lg) {
    return ((size_t)(r >> lg) << 10) + (size_t)(r & ((1 << lg) - 1));
}

#define GLOAD_LDS16(g, l) __builtin_amdgcn_global_load_lds( \
    (const __attribute__((address_space(1))) void*)(g), \
    (__attribute__((address_space(3))) void*)(l), 16, 0, 0)

// ---------------------------------------------------------------------------
// MFMA GEMM: C[mapRow(r,lgOut), n] = sum_k A[mapRow(r,lgIn), k]*Wt[n, k] + bias[n]
// A bf16 (M x K), Wt bf16 (512 x K, transposed weights), bias fp32.
// Tile 128x128, BK=32, 256 threads (4 waves, 2x2 of 64x64 per wave).
// ---------------------------------------------------------------------------
template <bool C_BF16>
__global__ __launch_bounds__(256) void gemm_mfma(
    const u16* __restrict__ A, const u16* __restrict__ Wt,
    const float* __restrict__ bias, void* __restrict__ Cv,
    int K, int lgIn, int lgOut)
{
    __shared__ u16 As[128 * 32];
    __shared__ u16 Bs[128 * 32];
    const int tid = threadIdx.x;
    const int lane = tid & 63;
    const int wid = tid >> 6;
    const int wr = wid >> 1, wc = wid & 1;
    const int row0 = blockIdx.x * 128;
    const int n0 = blockIdx.y * 128;

    // staging: wave wid owns chunks {2wid, 2wid+1} of A and of B (16 rows/1KB each)
    const int sr0 = wid * 32 + (lane >> 2);       // tile row of chunk 2wid
    const int sr1 = sr0 + 16;                     // tile row of chunk 2wid+1
    const int kp = (lane & 3) * 8;                // k element offset within row
    const u16* aSrc0 = A + mapRow(row0 + sr0, lgIn) * (size_t)K + kp;
    const u16* aSrc1 = A + mapRow(row0 + sr1, lgIn) * (size_t)K + kp;
    const u16* bSrc0 = Wt + (size_t)(n0 + sr0) * K + kp;
    const u16* bSrc1 = Wt + (size_t)(n0 + sr1) * K + kp;
    u16* aDst0 = &As[wid * 1024];
    u16* aDst1 = &As[wid * 1024 + 512];
    u16* bDst0 = &Bs[wid * 1024];
    u16* bDst1 = &Bs[wid * 1024 + 512];

    f32x4 acc[4][4];
#pragma unroll
    for (int mr = 0; mr < 4; ++mr)
#pragma unroll
        for (int nr = 0; nr < 4; ++nr)
            acc[mr][nr] = (f32x4){0.f, 0.f, 0.f, 0.f};

    const int koff = (lane >> 4) * 8;   // fragment k-offset (elements)
    const int fr = lane & 15;

    for (int k0 = 0; k0 < K; k0 += 32) {
        GLOAD_LDS16(aSrc0 + k0, aDst0);
        GLOAD_LDS16(aSrc1 + k0, aDst1);
        GLOAD_LDS16(bSrc0 + k0, bDst0);
        GLOAD_LDS16(bSrc1 + k0, bDst1);
        __syncthreads();                 // drains vmcnt(0): tiles resident
        i32x4 af[4], bf[4];
#pragma unroll
        for (int mr = 0; mr < 4; ++mr)
            af[mr] = *(const i32x4*)&As[(wr * 64 + mr * 16 + fr) * 32 + koff];
#pragma unroll
        for (int nr = 0; nr < 4; ++nr)
            bf[nr] = *(const i32x4*)&Bs[(wc * 64 + nr * 16 + fr) * 32 + koff];
#pragma unroll
        for (int mr = 0; mr < 4; ++mr)
#pragma unroll
            for (int nr = 0; nr < 4; ++nr)
                asm volatile("v_mfma_f32_16x16x32_bf16 %0, %1, %2, %0"
                             : "+v"(acc[mr][nr]) : "v"(af[mr]), "v"(bf[nr]));
        __syncthreads();                 // protect LDS before next stage
    }
    // MFMA -> VALU read hazard guard (inline asm bypasses compiler hazard nops)
    asm volatile("s_nop 7\n\ts_nop 7\n\ts_nop 7");

    float bv[4];
#pragma unroll
    for (int nr = 0; nr < 4; ++nr) bv[nr] = bias[n0 + wc * 64 + nr * 16 + fr];
    const int rbase = row0 + wr * 64 + (lane >> 4) * 4;
#pragma unroll
    for (int mr = 0; mr < 4; ++mr) {
#pragma unroll
        for (int j = 0; j < 4; ++j) {
            size_t orow = mapRow(rbase + mr * 16 + j, lgOut);
#pragma unroll
            for (int nr = 0; nr < 4; ++nr) {
                float v = acc[mr][nr][j] + bv[nr];
                int col = n0 + wc * 64 + nr * 16 + fr;
                if constexpr (C_BF16)
                    ((u16*)Cv)[orow * CD + col] = f2bf(v);
                else
                    ((float*)Cv)[orow * CD + col] = v;
            }
        }
    }
}

// flat fp32 -> bf16 conversion (vectorized, n multiple of 4)
__global__ __launch_bounds__(256) void cvt_f32_bf16(
    const float* __restrict__ in, u16* __restrict__ out, int n4)
{
    int i = blockIdx.x * 256 + threadIdx.x;
    if (i < n4) {
        float4 v = ((const float4*)in)[i];
        ((ushort4*)out)[i] = make_ushort4(f2bf(v.x), f2bf(v.y), f2bf(v.z), f2bf(v.w));
    }
}

// W (K x 512 fp32) -> Wt (512 x K bf16), 32x32 LDS tiles. block (32,8).
__global__ void transpose_w(const float* __restrict__ W, u16* __restrict__ Wt, int K)
{
    __shared__ u16 t[32][33];
    int k0 = blockIdx.x * 32, n0 = blockIdx.y * 32;
    int tx = threadIdx.x, ty = threadIdx.y;
#pragma unroll
    for (int i = 0; i < 4; ++i)
        t[ty + i * 8][tx] = f2bf(W[(size_t)(k0 + ty + i * 8) * 512 + n0 + tx]);
    __syncthreads();
#pragma unroll
    for (int i = 0; i < 4; ++i)
        Wt[(size_t)(n0 + ty + i * 8) * K + k0 + tx] = t[tx][ty + i * 8];
}

// Fill pad rows [Lstart, S) of a (B,S,D) bf16 buffer with the fp32 bias row.
__global__ void fill_rows_bf16(u16* __restrict__ dst, const float* __restrict__ bias,
                               int Lstart)
{
    int s = Lstart + blockIdx.x;
    int b = blockIdx.y;
    ushort4* r = (ushort4*)(dst + ((size_t)b * CS + s) * CD);
    int c = threadIdx.x;  // 128 threads, 4 elems each
    float4 bv = ((const float4*)bias)[c];
    r[c] = make_ushort4(f2bf(bv.x), f2bf(bv.y), f2bf(bv.z), f2bf(bv.w));
}

// Zero pad rows [Lstart, S) of a (B,S,D) bf16 buffer.
__global__ void zero_rows_bf16(u16* __restrict__ dst, int Lstart)
{
    int s = Lstart + blockIdx.x;
    int b = blockIdx.y;
    ushort4* r = (ushort4*)(dst + ((size_t)b * CS + s) * CD);
    r[threadIdx.x] = make_ushort4(0, 0, 0, 0);
}

// scores[bR*8 + beta] = sum_{e<64} q[bR, 64*beta+e] * k[bR, 64*beta+e]
__global__ __launch_bounds__(256) void scores_kernel(
    const u16* __restrict__ q, const u16* __restrict__ k,
    float* __restrict__ scoresM)
{
    int bR = blockIdx.x * 4 + (threadIdx.x >> 6);
    int lane = threadIdx.x & 63;
    const u16* qp = q + (size_t)bR * CD + lane;
    const u16* kp = k + (size_t)bR * CD + lane;
    float p[8];
#pragma unroll
    for (int i = 0; i < 8; ++i) p[i] = bf2f(qp[i * 64]) * bf2f(kp[i * 64]);
#pragma unroll
    for (int off = 32; off >= 1; off >>= 1) {
#pragma unroll
        for (int i = 0; i < 8; ++i) p[i] += __shfl_xor(p[i], off, 64);
    }
    if (lane == 0) {
        float4* o = (float4*)(scoresM + (size_t)bR * 8);
        o[0] = make_float4(p[0], p[1], p[2], p[3]);
        o[1] = make_float4(p[4], p[5], p[6], p[7]);
    }
}

// Per-batch reductions: 3x3 Gram F and angular cos numerators.
__global__ __launch_bounds__(256) void stats_kernel(
    const u16* __restrict__ feats, float* __restrict__ accum)
{
    int b = blockIdx.x >> 5;
    int chunk = blockIdx.x & 31;
    int wave = threadIdx.x >> 6, lane = threadIdx.x & 63;
    float a0 = 0, a1 = 0, a2 = 0, a3 = 0, a4 = 0, a5 = 0, a6 = 0, a7 = 0, a8 = 0;
    const u16* base = feats + (size_t)b * CS * CD + lane;
    for (int t = 0; t < 8; ++t) {
        int s = (chunk << 5) + (wave << 3) + t;
        const u16* f0 = base + (size_t)s * CD;
        const u16* f1 = f0 + CBSD;
        const u16* f2 = f1 + CBSD;
        float d00 = 0, d11 = 0, d22 = 0, d01 = 0, d02 = 0, d12 = 0;
#pragma unroll
        for (int j = 0; j < 8; ++j) {
            float x0 = bf2f(f0[j * 64]), x1 = bf2f(f1[j * 64]), x2 = bf2f(f2[j * 64]);
            d00 = fmaf(x0, x0, d00); d11 = fmaf(x1, x1, d11); d22 = fmaf(x2, x2, d22);
            d01 = fmaf(x0, x1, d01); d02 = fmaf(x0, x2, d02); d12 = fmaf(x1, x2, d12);
        }
#pragma unroll
        for (int off = 32; off >= 1; off >>= 1) {
            d00 += __shfl_xor(d00, off, 64);
            d11 += __shfl_xor(d11, off, 64);
            d22 += __shfl_xor(d22, off, 64);
            d01 += __shfl_xor(d01, off, 64);
            d02 += __shfl_xor(d02, off, 64);
            d12 += __shfl_xor(d12, off, 64);
        }
        float n0 = fmaxf(sqrtf(d00), 1e-12f);
        float n1 = fmaxf(sqrtf(d11), 1e-12f);
        float n2 = fmaxf(sqrtf(d22), 1e-12f);
        a0 += d00; a1 += d11; a2 += d22; a3 += d01; a4 += d02; a5 += d12;
        a6 += d01 / (n0 * n1); a7 += d02 / (n0 * n2); a8 += d12 / (n1 * n2);
    }
    if (lane == 0) {
        float* acc = accum + b * 9;
        atomicAdd(acc + 0, a0); atomicAdd(acc + 1, a1); atomicAdd(acc + 2, a2);
        atomicAdd(acc + 3, a3); atomicAdd(acc + 4, a4); atomicAdd(acc + 5, a5);
        atomicAdd(acc + 6, a6); atomicAdd(acc + 7, a7); atomicAdd(acc + 8, a8);
    }
}

// coef[0]=1/(8|t|), coef[1]=w0, coef[4+b*3+i] = w1*aw[b,i] + w2*cw[b,i].
__global__ void finalize_kernel(const float* __restrict__ accum,
                                const float* __restrict__ temp,
                                const float* __restrict__ attw,
                                const float* __restrict__ rolew,
                                float* __restrict__ coef)
{
    float t_abs = fabsf(temp[0]);
    float x0 = attw[0], x1 = attw[1], x2 = attw[2];
    float mx = fmaxf(x0, fmaxf(x1, x2));
    float e0 = expf(x0 - mx), e1 = expf(x1 - mx), e2 = expf(x2 - mx);
    float inv = 1.0f / (e0 + e1 + e2);
    float w0 = e0 * inv, w1 = e1 * inv, w2 = e2 * inv;
    int b = threadIdx.x;
    if (b == 0) { coef[0] = 1.0f / (8.0f * t_abs); coef[1] = w0; }
    if (b < CB) {
        const float* A = accum + b * 9;
        float Fm[3][3];
        Fm[0][0] = A[0]; Fm[1][1] = A[1]; Fm[2][2] = A[2];
        Fm[0][1] = Fm[1][0] = A[3];
        Fm[0][2] = Fm[2][0] = A[4];
        Fm[1][2] = Fm[2][1] = A[5];
        float cn[3] = {A[6], A[7], A[8]};   // (0,1) (0,2) (1,2)
        float eij[3];
#pragma unroll
        for (int p = 0; p < 3; ++p) {
            float c = cn[p] * (1.0f / 1024.0f);
            c = fminf(fmaxf(c, -1.0f + 1e-7f), 1.0f - 1e-7f);
            eij[p] = expf(-acosf(c) / t_abs);
        }
        float r0 = rolew[0], r1 = rolew[1], r2 = rolew[2];
        float as0 = r1 * eij[0] + r2 * eij[1];
        float as1 = r0 * eij[0] + r2 * eij[2];
        float as2 = r0 * eij[1] + r1 * eij[2];
        float amx = fmaxf(as0, fmaxf(as1, as2));
        float ea0 = expf(as0 - amx), ea1 = expf(as1 - amx), ea2 = expf(as2 - amx);
        float ainv = 1.0f / (ea0 + ea1 + ea2);
        float awv[3] = {ea0 * ainv, ea1 * ainv, ea2 * ainv};
        const float CA = 0.70710678118654752440f;   // cos(pi/4)
        const float C2 = 6.123233995736766e-17f;    // cos(pi/2)
        float vols[3];
#pragma unroll
        for (int i = 0; i < 3; ++i) {
            int j1 = (i + 1) % 3, j2 = (i + 2) % 3;
            float G00 = Fm[i][i];
            float G11 = CA * CA * (Fm[i][i] + 2.0f * Fm[i][j1] + Fm[j1][j1]);
            float G22 = C2 * C2 * Fm[i][i] + 2.0f * C2 * Fm[i][j2] + Fm[j2][j2];
            float G01 = CA * (Fm[i][i] + Fm[i][j1]);
            float G02 = C2 * Fm[i][i] + Fm[i][j2];
            float G12 = CA * (C2 * (Fm[i][i] + Fm[i][j1]) + Fm[i][j2] + Fm[j1][j2]);
            vols[i] = (4.0f / 9.0f) * ((G00 + G11 + G22) - (G01 + G02 + G12));
        }
        float vmx = fmaxf(vols[0], fmaxf(vols[1], vols[2]));
        float ev0 = expf((vols[0] - vmx) / t_abs);
        float ev1 = expf((vols[1] - vmx) / t_abs);
        float ev2 = expf((vols[2] - vmx) / t_abs);
        float vinv = 1.0f / (ev0 + ev1 + ev2);
        coef[4 + b * 3 + 0] = w1 * awv[0] + w2 * (ev0 * vinv);
        coef[4 + b * 3 + 1] = w1 * awv[1] + w2 * (ev1 * vinv);
        coef[4 + b * 3 + 2] = w1 * awv[2] + w2 * (ev2 * vinv);
    }
}

// fused accumulation over m-passes (m==0 also adds angular+cayley terms)
__global__ __launch_bounds__(256) void blend_kernel(
    const u16* __restrict__ vbuf, const u16* __restrict__ feats,
    const float* __restrict__ scores, const float* __restrict__ coef,
    u16* __restrict__ fused, int m)
{
    int bR = blockIdx.x;
    int b = bR >> 10, R = bR & 1023;
    float inv_scale = coef[0], w0 = coef[1];
    float g0 = coef[4 + b * 3 + 0];
    float g1 = coef[4 + b * 3 + 1];
    float g2 = coef[4 + b * 3 + 2];
    int h = R >> 7;
    int spBase = (R & 127) << 3;
#pragma unroll
    for (int it = 0; it < 2; ++it) {
        int c = (it << 8) + threadIdx.x;
        int beta = c >> 6, e = c & 63;
        size_t sidx = (size_t)bR * 8 + beta;
        float s0 = scores[sidx] * inv_scale;
        float s1 = scores[(size_t)CBS * 8 + sidx] * inv_scale;
        float s2 = scores[(size_t)2 * CBS * 8 + sidx] * inv_scale;
        float mxs = fmaxf(s0, fmaxf(s1, s2));
        float ex0 = expf(s0 - mxs), ex1 = expf(s1 - mxs), ex2 = expf(s2 - mxs);
        float sel = (m == 0) ? ex0 : ((m == 1) ? ex1 : ex2);
        float attn = sel / (ex0 + ex1 + ex2);
        float v = bf2f(vbuf[(size_t)bR * CD + c]);
        int sp = spBase + beta;
        int dp = (h << 6) + e;
        size_t off = ((size_t)(b << 10) + sp) * CD + dp;
        float val = w0 * attn * v;
        if (m == 0) {
            val += g0 * bf2f(feats[off]) + g1 * bf2f(feats[off + CBSD])
                 + g2 * bf2f(feats[off + 2 * CBSD]);
            fused[off] = f2bf(val);
        } else {
            fused[off] = f2bf(bf2f(fused[off]) + val);
        }
    }
}

extern "C" void kernel_launch(void* const* d_in, const int* in_sizes, int n_in,
                              void* d_out, int out_size, void* d_ws, size_t ws_size,
                              hipStream_t stream)
{
    const float* text  = (const float*)d_in[0];
    const float* image = (const float*)d_in[1];
    const float* audio = (const float*)d_in[2];
    const float* W0 = (const float*)d_in[3];  const float* b0 = (const float*)d_in[4];
    const float* W1 = (const float*)d_in[5];  const float* b1 = (const float*)d_in[6];
    const float* W2 = (const float*)d_in[7];  const float* b2 = (const float*)d_in[8];
    const float* Wq = (const float*)d_in[9];  const float* bq = (const float*)d_in[10];
    const float* Wk = (const float*)d_in[11]; const float* bk = (const float*)d_in[12];
    const float* Wv = (const float*)d_in[13]; const float* bv = (const float*)d_in[14];
    const float* Wo = (const float*)d_in[15]; const float* bo = (const float*)d_in[16];
    const float* temp  = (const float*)d_in[17];
    const float* attw  = (const float*)d_in[18];
    const float* rolew = (const float*)d_in[19];

    // ws layout (~171.4 MB, same footprint class as passing R2)
    u16* feats  = (u16*)d_ws;                 // 3*CBSD bf16
    u16* kv     = feats + 3 * CBSD;           // CBSD bf16 (input-cvt staging, K, V)
    u16* fused  = kv + CBSD;                  // CBSD bf16
    float* scores = (float*)(fused + CBSD);   // 3*CBS*8 f32
    float* accum  = scores + (size_t)3 * CBS * 8;  // 320 f32
    float* coef   = accum + 320;              // 128 f32
    u16* wot      = (u16*)(coef + 128);       // 512*512 bf16 (Wo^T — must NOT be in d_out)

    // d_out tail as scratch for q and the other transposed weights
    u16* q = (u16*)d_out;                     // CBSD bf16; dead before final GEMM
    u16* wpool = q + CBSD;                    // 1,966,080 bf16 (fits in 67MB d_out)
    u16* w0t = wpool;                         // 512*768
    u16* w1t = w0t + 512 * 768;               // 512*1024
    u16* w2t = w1t + 512 * 1024;              // 512*512
    u16* wqt = w2t + 512 * 512;
    u16* wkt = wqt + 512 * 512;
    u16* wvt = wkt + 512 * 512;

    const dim3 blk(256);
    const dim3 tblk(32, 8);
    const int Lm[3] = {512, 256, 1024};
    const int lg[3] = {9, 8, 10};
    const float* bm[3] = {b0, b1, b2};
    const float* xm[3] = {text, image, audio};
    u16* wmt[3] = {w0t, w1t, w2t};
    const int Km[3] = {768, 1024, 512};

    // pad rows of feats to zero (mod2 has none); accum zero for atomics
    zero_rows_bf16<<<dim3(512, CB), dim3(128), 0, stream>>>(feats, 512);
    zero_rows_bf16<<<dim3(768, CB), dim3(128), 0, stream>>>(feats + CBSD, 256);
    hipMemsetAsync(accum, 0, 320 * sizeof(float), stream);

    // weight transposes (fp32 -> bf16, K x 512 -> 512 x K)
    transpose_w<<<dim3(24, 16), tblk, 0, stream>>>(W0, w0t, 768);
    transpose_w<<<dim3(32, 16), tblk, 0, stream>>>(W1, w1t, 1024);
    transpose_w<<<dim3(16, 16), tblk, 0, stream>>>(W2, w2t, 512);
    transpose_w<<<dim3(16, 16), tblk, 0, stream>>>(Wq, wqt, 512);
    transpose_w<<<dim3(16, 16), tblk, 0, stream>>>(Wk, wkt, 512);
    transpose_w<<<dim3(16, 16), tblk, 0, stream>>>(Wv, wvt, 512);
    transpose_w<<<dim3(16, 16), tblk, 0, stream>>>(Wo, wot, 512);

    // input projections: cvt input -> kv (bf16), MFMA GEMM -> feats
    for (int m = 0; m < 3; ++m) {
        int n = CB * Lm[m] * Km[m];
        cvt_f32_bf16<<<dim3(n / 1024), blk, 0, stream>>>(xm[m], kv, n / 4);
        gemm_mfma<true><<<dim3(CB * Lm[m] / 128, 4), blk, 0, stream>>>(
            kv, wmt[m], bm[m], feats + (size_t)m * CBSD, Km[m], 10, lg[m]);
    }

    // Q projection (real rows) + bias fill for pad rows
    gemm_mfma<true><<<dim3(128, 4), blk, 0, stream>>>(feats, wqt, bq, q, 512, 9, 9);
    fill_rows_bf16<<<dim3(512, CB), dim3(128), 0, stream>>>(q, bq, 512);

    // angular + Cayley stats
    stats_kernel<<<dim3(CB * 32), blk, 0, stream>>>(feats, accum);
    finalize_kernel<<<dim3(1), dim3(64), 0, stream>>>(accum, temp, attw, rolew, coef);

    // K per modality -> scores
    for (int m = 0; m < 3; ++m) {
        gemm_mfma<true><<<dim3(CB * Lm[m] / 128, 4), blk, 0, stream>>>(
            feats + (size_t)m * CBSD, wkt, bk, kv, 512, lg[m], lg[m]);
        if (Lm[m] < CS)
            fill_rows_bf16<<<dim3(CS - Lm[m], CB), dim3(128), 0, stream>>>(kv, bk, Lm[m]);
        scores_kernel<<<dim3(CBS / 4), blk, 0, stream>>>(q, kv, scores + (size_t)m * CBS * 8);
    }

    // V per modality -> blend into fused
    for (int m = 0; m < 3; ++m) {
        gemm_mfma<true><<<dim3(CB * Lm[m] / 128, 4), blk, 0, stream>>>(
            feats + (size_t)m * CBSD, wvt, bv, kv, 512, lg[m], lg[m]);
        if (Lm[m] < CS)
            fill_rows_bf16<<<dim3(CS - Lm[m], CB), dim3(128), 0, stream>>>(kv, bv, Lm[m]);
        blend_kernel<<<dim3(CBS), blk, 0, stream>>>(kv, feats, scores, coef, fused, m);
    }

    // output projection (Wo^T lives in ws -> no race with d_out stores)
    gemm_mfma<false><<<dim3(256, 4), blk, 0, stream>>>(fused, wot, bo, (float*)d_out, 512, 10, 10);
}

// Round 5
// 632.435 us; speedup vs baseline: 3.3840x; 1.2527x over previous
//
#include <hip/hip_runtime.h>
#include <hip/hip_bf16.h>

// GeometricModalityFusion — Round 5.
// R4 passed @792us, absmax 0.0039. Top cost: stats_kernel 84us (scalar bf16
// loads). This round: vectorize stats+scores (16B/lane), fuse blend into the
// V-GEMM epilogue (EPI=2) with a blend_init pass for g-feats + pad-row attn
// terms, merge the 5 square transposes into one dispatch.
//
// Semantics (verified passing R2/R4):
//  * raw reshape: per (row R, 64-col block beta): 64-dot, softmax over M=3,
//    blend of V rows, scatter to row s'=(R%128)*8+beta, cols [64*(R/128),+64).
//  * pad rows of feats are 0 -> K/V/Q pad rows == bias row.
//  * Cayley needs only per-batch 3x3 Gram; angular needs per-position
//    normalized cross-dots summed over s -> per-batch coefficients.

constexpr int CB = 32;
constexpr int CS = 1024;
constexpr int CD = 512;
constexpr int CBS = CB * CS;                  // 32768
constexpr size_t CBSD = (size_t)CBS * CD;     // 16,777,216 elements

typedef unsigned short u16;
typedef float f32x4 __attribute__((ext_vector_type(4)));
typedef int i32x4 __attribute__((ext_vector_type(4)));

__device__ __forceinline__ float bf2f(u16 u) {
    return __uint_as_float(((unsigned)u) << 16);
}
__device__ __forceinline__ float bfLO(int w) {
    return __uint_as_float(((unsigned)w) << 16);
}
__device__ __forceinline__ float bfHI(int w) {
    return __uint_as_float((unsigned)w & 0xffff0000u);
}
__device__ __forceinline__ u16 f2bf(float f) {
    unsigned u = __float_as_uint(f);
    return (u16)((u + 0x7FFFu + ((u >> 16) & 1u)) >> 16);
}
__device__ __forceinline__ size_t mapRow(int r, int lg) {
    return ((size_t)(r >> lg) << 10) + (size_t)(r & ((1 << lg) - 1));
}

#define GLOAD_LDS16(g, l) __builtin_amdgcn_global_load_lds( \
    (const __attribute__((address_space(1))) void*)(g), \
    (__attribute__((address_space(3))) void*)(l), 16, 0, 0)

// ---------------------------------------------------------------------------
// MFMA GEMM: 128x128 tile, BK=32, 4 waves (2x2 of 64x64), 16B global_load_lds.
// EPI=0: C bf16.  EPI=1: C fp32.  EPI=2: blend-scatter RMW into `fused`
//   (fused[off] += w0*attn_m*(acc+bias), off = de-reshaped scatter location).
// ---------------------------------------------------------------------------
template <int EPI>
__global__ __launch_bounds__(256) void gemm_mfma(
    const u16* __restrict__ A, const u16* __restrict__ Wt,
    const float* __restrict__ bias, void* __restrict__ Cv,
    int K, int lgIn, int lgOut,
    const float* __restrict__ scores, const float* __restrict__ coef,
    u16* __restrict__ fused, int m)
{
    __shared__ u16 As[128 * 32];
    __shared__ u16 Bs[128 * 32];
    __shared__ float attnw[256];     // EPI==2: w0*attn_m per (row, beta-half)
    const int tid = threadIdx.x;
    const int lane = tid & 63;
    const int wid = tid >> 6;
    const int wr = wid >> 1, wc = wid & 1;
    const int row0 = blockIdx.x * 128;
    const int n0 = blockIdx.y * 128;

    const int sr0 = wid * 32 + (lane >> 2);
    const int sr1 = sr0 + 16;
    const int kp = (lane & 3) * 8;
    const u16* aSrc0 = A + mapRow(row0 + sr0, lgIn) * (size_t)K + kp;
    const u16* aSrc1 = A + mapRow(row0 + sr1, lgIn) * (size_t)K + kp;
    const u16* bSrc0 = Wt + (size_t)(n0 + sr0) * K + kp;
    const u16* bSrc1 = Wt + (size_t)(n0 + sr1) * K + kp;
    u16* aDst0 = &As[wid * 1024];
    u16* aDst1 = &As[wid * 1024 + 512];
    u16* bDst0 = &Bs[wid * 1024];
    u16* bDst1 = &Bs[wid * 1024 + 512];

    f32x4 acc[4][4];
#pragma unroll
    for (int mr = 0; mr < 4; ++mr)
#pragma unroll
        for (int nr = 0; nr < 4; ++nr)
            acc[mr][nr] = (f32x4){0.f, 0.f, 0.f, 0.f};

    const int koff = (lane >> 4) * 8;
    const int fr = lane & 15;

    for (int k0 = 0; k0 < K; k0 += 32) {
        GLOAD_LDS16(aSrc0 + k0, aDst0);
        GLOAD_LDS16(aSrc1 + k0, aDst1);
        GLOAD_LDS16(bSrc0 + k0, bDst0);
        GLOAD_LDS16(bSrc1 + k0, bDst1);
        __syncthreads();
        i32x4 af[4], bf[4];
#pragma unroll
        for (int mr = 0; mr < 4; ++mr)
            af[mr] = *(const i32x4*)&As[(wr * 64 + mr * 16 + fr) * 32 + koff];
#pragma unroll
        for (int nr = 0; nr < 4; ++nr)
            bf[nr] = *(const i32x4*)&Bs[(wc * 64 + nr * 16 + fr) * 32 + koff];
#pragma unroll
        for (int mr = 0; mr < 4; ++mr)
#pragma unroll
            for (int nr = 0; nr < 4; ++nr)
                asm volatile("v_mfma_f32_16x16x32_bf16 %0, %1, %2, %0"
                             : "+v"(acc[mr][nr]) : "v"(af[mr]), "v"(bf[nr]));
        __syncthreads();
    }
    asm volatile("s_nop 7\n\ts_nop 7\n\ts_nop 7");

    if constexpr (EPI == 2) {
        // attn weights: 256 threads cover (row r<128, beta-half bi<2)
        int r = tid >> 1, bi = tid & 1;
        size_t orow = mapRow(row0 + r, lgOut);
        size_t sidx = orow * 8 + (n0 >> 6) + bi;
        float inv_scale = coef[0], w0c = coef[1];
        float s0 = scores[sidx] * inv_scale;
        float s1 = scores[(size_t)CBS * 8 + sidx] * inv_scale;
        float s2 = scores[(size_t)2 * CBS * 8 + sidx] * inv_scale;
        float mx = fmaxf(s0, fmaxf(s1, s2));
        float e0 = __expf(s0 - mx), e1 = __expf(s1 - mx), e2 = __expf(s2 - mx);
        float sel = (m == 0) ? e0 : ((m == 1) ? e1 : e2);
        attnw[tid] = w0c * sel / (e0 + e1 + e2);
        __syncthreads();
    }

    float bv[4];
#pragma unroll
    for (int nr = 0; nr < 4; ++nr) bv[nr] = bias[n0 + wc * 64 + nr * 16 + fr];
    const int rloc0 = wr * 64 + (lane >> 4) * 4;
#pragma unroll
    for (int mr = 0; mr < 4; ++mr) {
#pragma unroll
        for (int j = 0; j < 4; ++j) {
            const int rloc = rloc0 + mr * 16 + j;
            size_t orow = mapRow(row0 + rloc, lgOut);
            if constexpr (EPI == 2) {
                int b = (int)(orow >> 10), R = (int)(orow & 1023);
                float aw = attnw[rloc * 2 + wc];
                int spBase = ((R & 127) << 3);
                int dpBase = ((R >> 7) << 6);
#pragma unroll
                for (int nr = 0; nr < 4; ++nr) {
                    int cg = n0 + wc * 64 + nr * 16 + fr;
                    float v = acc[mr][nr][j] + bv[nr];
                    size_t off = ((size_t)(b << 10) + spBase + (cg >> 6)) * CD
                               + dpBase + (cg & 63);
                    fused[off] = f2bf(bf2f(fused[off]) + aw * v);
                }
            } else {
#pragma unroll
                for (int nr = 0; nr < 4; ++nr) {
                    float v = acc[mr][nr][j] + bv[nr];
                    int col = n0 + wc * 64 + nr * 16 + fr;
                    if constexpr (EPI == 0)
                        ((u16*)Cv)[orow * CD + col] = f2bf(v);
                    else
                        ((float*)Cv)[orow * CD + col] = v;
                }
            }
        }
    }
}

// flat fp32 -> bf16 conversion (vectorized, n multiple of 4)
__global__ __launch_bounds__(256) void cvt_f32_bf16(
    const float* __restrict__ in, u16* __restrict__ out, int n4)
{
    int i = blockIdx.x * 256 + threadIdx.x;
    if (i < n4) {
        float4 v = ((const float4*)in)[i];
        ((ushort4*)out)[i] = make_ushort4(f2bf(v.x), f2bf(v.y), f2bf(v.z), f2bf(v.w));
    }
}

// W (K x 512 fp32) -> Wt (512 x K bf16), 32x32 LDS tiles. block (32,8).
__global__ void transpose_w(const float* __restrict__ W, u16* __restrict__ Wt, int K)
{
    __shared__ u16 t[32][33];
    int k0 = blockIdx.x * 32, n0 = blockIdx.y * 32;
    int tx = threadIdx.x, ty = threadIdx.y;
#pragma unroll
    for (int i = 0; i < 4; ++i)
        t[ty + i * 8][tx] = f2bf(W[(size_t)(k0 + ty + i * 8) * 512 + n0 + tx]);
    __syncthreads();
#pragma unroll
    for (int i = 0; i < 4; ++i)
        Wt[(size_t)(n0 + ty + i * 8) * K + k0 + tx] = t[tx][ty + i * 8];
}

// five 512x512 transposes in one dispatch (blockIdx.z selects the pair)
struct TP5 { const float* src[5]; u16* dst[5]; };
__global__ void transpose5(TP5 tp)
{
    __shared__ u16 t[32][33];
    const float* W = tp.src[blockIdx.z];
    u16* Wt = tp.dst[blockIdx.z];
    int k0 = blockIdx.x * 32, n0 = blockIdx.y * 32;
    int tx = threadIdx.x, ty = threadIdx.y;
#pragma unroll
    for (int i = 0; i < 4; ++i)
        t[ty + i * 8][tx] = f2bf(W[(size_t)(k0 + ty + i * 8) * 512 + n0 + tx]);
    __syncthreads();
#pragma unroll
    for (int i = 0; i < 4; ++i)
        Wt[(size_t)(n0 + ty + i * 8) * 512 + k0 + tx] = t[tx][ty + i * 8];
}

// Fill pad rows [Lstart, S) of a (B,S,D) bf16 buffer with the fp32 bias row.
__global__ void fill_rows_bf16(u16* __restrict__ dst, const float* __restrict__ bias,
                               int Lstart)
{
    int s = Lstart + blockIdx.x;
    int b = blockIdx.y;
    ushort4* r = (ushort4*)(dst + ((size_t)b * CS + s) * CD);
    int c = threadIdx.x;
    float4 bv = ((const float4*)bias)[c];
    r[c] = make_ushort4(f2bf(bv.x), f2bf(bv.y), f2bf(bv.z), f2bf(bv.w));
}

// Zero pad rows [Lstart, S) of a (B,S,D) bf16 buffer.
__global__ void zero_rows_bf16(u16* __restrict__ dst, int Lstart)
{
    int s = Lstart + blockIdx.x;
    int b = blockIdx.y;
    ushort4* r = (ushort4*)(dst + ((size_t)b * CS + s) * CD);
    r[threadIdx.x] = make_ushort4(0, 0, 0, 0);
}

// scores[bR*8+beta] = sum_{e<64} q[bR,64*beta+e]*k[bR,64*beta+e]
// 16B/lane loads; 8-lane-group reduce; 4 waves x 8 rows per block.
__global__ __launch_bounds__(256) void scores_kernel(
    const u16* __restrict__ q, const u16* __restrict__ k,
    float* __restrict__ scoresM)
{
    int wave = threadIdx.x >> 6, lane = threadIdx.x & 63;
    int r0 = blockIdx.x * 32 + wave * 8;
    const u16* qb = q + (size_t)r0 * CD + lane * 8;
    const u16* kb = k + (size_t)r0 * CD + lane * 8;
#pragma unroll
    for (int t = 0; t < 8; ++t) {
        i32x4 qu = *(const i32x4*)(qb + t * CD);
        i32x4 ku = *(const i32x4*)(kb + t * CD);
        float p = 0.f;
#pragma unroll
        for (int j = 0; j < 4; ++j) {
            p = fmaf(bfLO(qu[j]), bfLO(ku[j]), p);
            p = fmaf(bfHI(qu[j]), bfHI(ku[j]), p);
        }
        p += __shfl_xor(p, 1, 64);
        p += __shfl_xor(p, 2, 64);
        p += __shfl_xor(p, 4, 64);
        if ((lane & 7) == 0)
            scoresM[(size_t)(r0 + t) * 8 + (lane >> 3)] = p;
    }
}

// Per-batch reductions: 3x3 Gram F and angular cos numerators (vectorized).
// Each wave: 16 rows; lane loads 8 contiguous cols per modality (16B).
__global__ __launch_bounds__(256) void stats_kernel(
    const u16* __restrict__ feats, float* __restrict__ accum)
{
    int wave = threadIdx.x >> 6, lane = threadIdx.x & 63;
    int chunk = blockIdx.x * 4 + wave;          // 2048 chunks x 16 rows
    int r0 = chunk * 16;
    int b = r0 >> 10;
    float a0 = 0, a1 = 0, a2 = 0, a3 = 0, a4 = 0, a5 = 0, a6 = 0, a7 = 0, a8 = 0;
    const u16* base = feats + (size_t)r0 * CD + lane * 8;
    for (int t = 0; t < 16; ++t) {
        const u16* f0 = base + (size_t)t * CD;
        i32x4 u0 = *(const i32x4*)f0;
        i32x4 u1 = *(const i32x4*)(f0 + CBSD);
        i32x4 u2 = *(const i32x4*)(f0 + 2 * CBSD);
        float d00 = 0, d11 = 0, d22 = 0, d01 = 0, d02 = 0, d12 = 0;
#pragma unroll
        for (int j = 0; j < 4; ++j) {
            float x0 = bfLO(u0[j]), y0 = bfHI(u0[j]);
            float x1 = bfLO(u1[j]), y1 = bfHI(u1[j]);
            float x2 = bfLO(u2[j]), y2 = bfHI(u2[j]);
            d00 = fmaf(x0, x0, d00); d00 = fmaf(y0, y0, d00);
            d11 = fmaf(x1, x1, d11); d11 = fmaf(y1, y1, d11);
            d22 = fmaf(x2, x2, d22); d22 = fmaf(y2, y2, d22);
            d01 = fmaf(x0, x1, d01); d01 = fmaf(y0, y1, d01);
            d02 = fmaf(x0, x2, d02); d02 = fmaf(y0, y2, d02);
            d12 = fmaf(x1, x2, d12); d12 = fmaf(y1, y2, d12);
        }
#pragma unroll
        for (int off = 32; off >= 1; off >>= 1) {
            d00 += __shfl_xor(d00, off, 64);
            d11 += __shfl_xor(d11, off, 64);
            d22 += __shfl_xor(d22, off, 64);
            d01 += __shfl_xor(d01, off, 64);
            d02 += __shfl_xor(d02, off, 64);
            d12 += __shfl_xor(d12, off, 64);
        }
        float n0 = fmaxf(sqrtf(d00), 1e-12f);
        float n1 = fmaxf(sqrtf(d11), 1e-12f);
        float n2 = fmaxf(sqrtf(d22), 1e-12f);
        a0 += d00; a1 += d11; a2 += d22; a3 += d01; a4 += d02; a5 += d12;
        a6 += d01 / (n0 * n1); a7 += d02 / (n0 * n2); a8 += d12 / (n1 * n2);
    }
    if (lane == 0) {
        float* acc = accum + b * 9;
        atomicAdd(acc + 0, a0); atomicAdd(acc + 1, a1); atomicAdd(acc + 2, a2);
        atomicAdd(acc + 3, a3); atomicAdd(acc + 4, a4); atomicAdd(acc + 5, a5);
        atomicAdd(acc + 6, a6); atomicAdd(acc + 7, a7); atomicAdd(acc + 8, a8);
    }
}

// coef[0]=1/(8|t|), coef[1]=w0, coef[4+b*3+i] = w1*aw[b,i] + w2*cw[b,i].
__global__ void finalize_kernel(const float* __restrict__ accum,
                                const float* __restrict__ temp,
                                const float* __restrict__ attw,
                                const float* __restrict__ rolew,
                                float* __restrict__ coef)
{
    float t_abs = fabsf(temp[0]);
    float x0 = attw[0], x1 = attw[1], x2 = attw[2];
    float mx = fmaxf(x0, fmaxf(x1, x2));
    float e0 = expf(x0 - mx), e1 = expf(x1 - mx), e2 = expf(x2 - mx);
    float inv = 1.0f / (e0 + e1 + e2);
    float w0 = e0 * inv, w1 = e1 * inv, w2 = e2 * inv;
    int b = threadIdx.x;
    if (b == 0) { coef[0] = 1.0f / (8.0f * t_abs); coef[1] = w0; }
    if (b < CB) {
        const float* A = accum + b * 9;
        float Fm[3][3];
        Fm[0][0] = A[0]; Fm[1][1] = A[1]; Fm[2][2] = A[2];
        Fm[0][1] = Fm[1][0] = A[3];
        Fm[0][2] = Fm[2][0] = A[4];
        Fm[1][2] = Fm[2][1] = A[5];
        float cn[3] = {A[6], A[7], A[8]};
        float eij[3];
#pragma unroll
        for (int p = 0; p < 3; ++p) {
            float c = cn[p] * (1.0f / 1024.0f);
            c = fminf(fmaxf(c, -1.0f + 1e-7f), 1.0f - 1e-7f);
            eij[p] = expf(-acosf(c) / t_abs);
        }
        float r0 = rolew[0], r1 = rolew[1], r2 = rolew[2];
        float as0 = r1 * eij[0] + r2 * eij[1];
        float as1 = r0 * eij[0] + r2 * eij[2];
        float as2 = r0 * eij[1] + r1 * eij[2];
        float amx = fmaxf(as0, fmaxf(as1, as2));
        float ea0 = expf(as0 - amx), ea1 = expf(as1 - amx), ea2 = expf(as2 - amx);
        float ainv = 1.0f / (ea0 + ea1 + ea2);
        float awv[3] = {ea0 * ainv, ea1 * ainv, ea2 * ainv};
        const float CA = 0.70710678118654752440f;   // cos(pi/4)
        const float C2 = 6.123233995736766e-17f;    // cos(pi/2)
        float vols[3];
#pragma unroll
        for (int i = 0; i < 3; ++i) {
            int j1 = (i + 1) % 3, j2 = (i + 2) % 3;
            float G00 = Fm[i][i];
            float G11 = CA * CA * (Fm[i][i] + 2.0f * Fm[i][j1] + Fm[j1][j1]);
            float G22 = C2 * C2 * Fm[i][i] + 2.0f * C2 * Fm[i][j2] + Fm[j2][j2];
            float G01 = CA * (Fm[i][i] + Fm[i][j1]);
            float G02 = C2 * Fm[i][i] + Fm[i][j2];
            float G12 = CA * (C2 * (Fm[i][i] + Fm[i][j1]) + Fm[i][j2] + Fm[j1][j2]);
            vols[i] = (4.0f / 9.0f) * ((G00 + G11 + G22) - (G01 + G02 + G12));
        }
        float vmx = fmaxf(vols[0], fmaxf(vols[1], vols[2]));
        float ev0 = expf((vols[0] - vmx) / t_abs);
        float ev1 = expf((vols[1] - vmx) / t_abs);
        float ev2 = expf((vols[2] - vmx) / t_abs);
        float vinv = 1.0f / (ev0 + ev1 + ev2);
        coef[4 + b * 3 + 0] = w1 * awv[0] + w2 * (ev0 * vinv);
        coef[4 + b * 3 + 1] = w1 * awv[1] + w2 * (ev1 * vinv);
        coef[4 + b * 3 + 2] = w1 * awv[2] + w2 * (ev2 * vinv);
    }
}

// fused init: g-weighted feats + pad-row attention terms (pad V row == bias).
__global__ __launch_bounds__(256) void blend_init(
    const u16* __restrict__ feats, const float* __restrict__ scores,
    const float* __restrict__ coef, const float* __restrict__ bv,
    u16* __restrict__ fused)
{
    int bR = blockIdx.x;
    int b = bR >> 10, R = bR & 1023;
    float inv_scale = coef[0], w0c = coef[1];
    float g0 = coef[4 + b * 3 + 0];
    float g1 = coef[4 + b * 3 + 1];
    float g2 = coef[4 + b * 3 + 2];
    int h = R >> 7;
    int spBase = (R & 127) << 3;
#pragma unroll
    for (int it = 0; it < 2; ++it) {
        int c = (it << 8) + threadIdx.x;
        int beta = c >> 6, e = c & 63;
        size_t off = ((size_t)(b << 10) + spBase + beta) * CD + (h << 6) + e;
        float val = g0 * bf2f(feats[off]) + g1 * bf2f(feats[off + CBSD])
                  + g2 * bf2f(feats[off + 2 * CBSD]);
        if (R >= 256) {   // pad-row attn terms exist only for R >= 256
            size_t sidx = (size_t)bR * 8 + beta;
            float s0 = scores[sidx] * inv_scale;
            float s1 = scores[(size_t)CBS * 8 + sidx] * inv_scale;
            float s2 = scores[(size_t)2 * CBS * 8 + sidx] * inv_scale;
            float mxs = fmaxf(s0, fmaxf(s1, s2));
            float ex0 = __expf(s0 - mxs), ex1 = __expf(s1 - mxs), ex2 = __expf(s2 - mxs);
            float den = ex0 + ex1 + ex2;
            float bvc = bv[c];
            float t = ex1;                       // m1 pad (image, L=256)
            if (R >= 512) t += ex0;              // m0 pad (text, L=512)
            val += w0c * (t / den) * bvc;
        }
        fused[off] = f2bf(val);
    }
}

extern "C" void kernel_launch(void* const* d_in, const int* in_sizes, int n_in,
                              void* d_out, int out_size, void* d_ws, size_t ws_size,
                              hipStream_t stream)
{
    const float* text  = (const float*)d_in[0];
    const float* image = (const float*)d_in[1];
    const float* audio = (const float*)d_in[2];
    const float* W0 = (const float*)d_in[3];  const float* b0 = (const float*)d_in[4];
    const float* W1 = (const float*)d_in[5];  const float* b1 = (const float*)d_in[6];
    const float* W2 = (const float*)d_in[7];  const float* b2 = (const float*)d_in[8];
    const float* Wq = (const float*)d_in[9];  const float* bq = (const float*)d_in[10];
    const float* Wk = (const float*)d_in[11]; const float* bk = (const float*)d_in[12];
    const float* Wv = (const float*)d_in[13]; const float* bv = (const float*)d_in[14];
    const float* Wo = (const float*)d_in[15]; const float* bo = (const float*)d_in[16];
    const float* temp  = (const float*)d_in[17];
    const float* attw  = (const float*)d_in[18];
    const float* rolew = (const float*)d_in[19];

    // ws layout (~171.4 MB, same as passing R4)
    u16* feats  = (u16*)d_ws;                 // 3*CBSD bf16
    u16* kv     = feats + 3 * CBSD;           // CBSD bf16 (cvt staging, K buffer)
    u16* fused  = kv + CBSD;                  // CBSD bf16
    float* scores = (float*)(fused + CBSD);   // 3*CBS*8 f32
    float* accum  = scores + (size_t)3 * CBS * 8;  // 320 f32
    float* coef   = accum + 320;              // 128 f32
    u16* wot      = (u16*)(coef + 128);       // 512*512 bf16 (NOT in d_out)

    // d_out tail as scratch
    u16* q = (u16*)d_out;                     // CBSD bf16; dead before final GEMM
    u16* wpool = q + CBSD;
    u16* w0t = wpool;                         // 512*768
    u16* w1t = w0t + 512 * 768;               // 512*1024
    u16* w2t = w1t + 512 * 1024;              // 512*512
    u16* wqt = w2t + 512 * 512;
    u16* wkt = wqt + 512 * 512;
    u16* wvt = wkt + 512 * 512;

    const dim3 blk(256);
    const dim3 tblk(32, 8);
    const int Lm[3] = {512, 256, 1024};
    const int lg[3] = {9, 8, 10};
    const float* bm[3] = {b0, b1, b2};
    const float* xm[3] = {text, image, audio};
    u16* wmt[3] = {w0t, w1t, w2t};
    const int Km[3] = {768, 1024, 512};

    zero_rows_bf16<<<dim3(512, CB), dim3(128), 0, stream>>>(feats, 512);
    zero_rows_bf16<<<dim3(768, CB), dim3(128), 0, stream>>>(feats + CBSD, 256);
    hipMemsetAsync(accum, 0, 320 * sizeof(float), stream);

    // weight transposes
    transpose_w<<<dim3(24, 16), tblk, 0, stream>>>(W0, w0t, 768);
    transpose_w<<<dim3(32, 16), tblk, 0, stream>>>(W1, w1t, 1024);
    TP5 tp;
    tp.src[0] = W2; tp.dst[0] = w2t;
    tp.src[1] = Wq; tp.dst[1] = wqt;
    tp.src[2] = Wk; tp.dst[2] = wkt;
    tp.src[3] = Wv; tp.dst[3] = wvt;
    tp.src[4] = Wo; tp.dst[4] = wot;
    transpose5<<<dim3(16, 16, 5), tblk, 0, stream>>>(tp);

    // input projections
    for (int m = 0; m < 3; ++m) {
        int n = CB * Lm[m] * Km[m];
        cvt_f32_bf16<<<dim3(n / 1024), blk, 0, stream>>>(xm[m], kv, n / 4);
        gemm_mfma<0><<<dim3(CB * Lm[m] / 128, 4), blk, 0, stream>>>(
            kv, wmt[m], bm[m], feats + (size_t)m * CBSD, Km[m], 10, lg[m],
            nullptr, nullptr, nullptr, 0);
    }

    // Q projection + pad fill
    gemm_mfma<0><<<dim3(128, 4), blk, 0, stream>>>(
        feats, wqt, bq, q, 512, 9, 9, nullptr, nullptr, nullptr, 0);
    fill_rows_bf16<<<dim3(512, CB), dim3(128), 0, stream>>>(q, bq, 512);

    // angular + Cayley stats
    stats_kernel<<<dim3(512), blk, 0, stream>>>(feats, accum);
    finalize_kernel<<<dim3(1), dim3(64), 0, stream>>>(accum, temp, attw, rolew, coef);

    // K per modality -> scores
    for (int m = 0; m < 3; ++m) {
        gemm_mfma<0><<<dim3(CB * Lm[m] / 128, 4), blk, 0, stream>>>(
            feats + (size_t)m * CBSD, wkt, bk, kv, 512, lg[m], lg[m],
            nullptr, nullptr, nullptr, 0);
        if (Lm[m] < CS)
            fill_rows_bf16<<<dim3(CS - Lm[m], CB), dim3(128), 0, stream>>>(kv, bk, Lm[m]);
        scores_kernel<<<dim3(CBS / 32), blk, 0, stream>>>(q, kv, scores + (size_t)m * CBS * 8);
    }

    // fused init (g-feats + pad-row attn terms), then V GEMMs scatter-blend
    blend_init<<<dim3(CBS), blk, 0, stream>>>(feats, scores, coef, bv, fused);
    for (int m = 0; m < 3; ++m) {
        gemm_mfma<2><<<dim3(CB * Lm[m] / 128, 4), blk, 0, stream>>>(
            feats + (size_t)m * CBSD, wvt, bv, nullptr, 512, lg[m], lg[m],
            scores, coef, fused, m);
    }

    // output projection
    gemm_mfma<1><<<dim3(256, 4), blk, 0, stream>>>(
        fused, wot, bo, (float*)d_out, 512, 10, 10, nullptr, nullptr, nullptr, 0);
}

// Round 6
// 600.766 us; speedup vs baseline: 3.5624x; 1.0527x over previous
//
#include <hip/hip_runtime.h>
#include <hip/hip_bf16.h>

// GeometricModalityFusion — Round 6.
// R5 passed @632us. stats still top (52us, latency-bound @13% occ) and the
// K->scores path re-reads 64MB x3. This round:
//  1) region-aware stats (pad rows contribute exactly 0 -> skip padded
//     modalities), 8-row chunks, 1024 blocks.
//  2) scores fused into K-GEMM epilogue (EPI=3): wave's 64-col half == one
//     beta block; dot with q + 16-lane shfl reduce -> scores. kv K-writes,
//     scores_kernel, K fill_rows all dropped. Pad-row scores via pad_scores
//     (k pad row == bk).
//
// Semantics (verified passing R2/R4/R5):
//  * raw reshape: per (row R, 64-col block beta): 64-dot, softmax over M=3,
//    blend of V rows, scatter to row s'=(R%128)*8+beta, cols [64*(R/128),+64).
//  * pad rows of feats are 0 -> K/V/Q pad rows == bias row.
//  * Cayley needs only per-batch 3x3 Gram; angular needs per-position
//    normalized cross-dots summed over s -> per-batch coefficients.

constexpr int CB = 32;
constexpr int CS = 1024;
constexpr int CD = 512;
constexpr int CBS = CB * CS;                  // 32768
constexpr size_t CBSD = (size_t)CBS * CD;     // 16,777,216 elements

typedef unsigned short u16;
typedef float f32x4 __attribute__((ext_vector_type(4)));
typedef int i32x4 __attribute__((ext_vector_type(4)));

__device__ __forceinline__ float bf2f(u16 u) {
    return __uint_as_float(((unsigned)u) << 16);
}
__device__ __forceinline__ float bfLO(int w) {
    return __uint_as_float(((unsigned)w) << 16);
}
__device__ __forceinline__ float bfHI(int w) {
    return __uint_as_float((unsigned)w & 0xffff0000u);
}
__device__ __forceinline__ u16 f2bf(float f) {
    unsigned u = __float_as_uint(f);
    return (u16)((u + 0x7FFFu + ((u >> 16) & 1u)) >> 16);
}
__device__ __forceinline__ size_t mapRow(int r, int lg) {
    return ((size_t)(r >> lg) << 10) + (size_t)(r & ((1 << lg) - 1));
}

#define GLOAD_LDS16(g, l) __builtin_amdgcn_global_load_lds( \
    (const __attribute__((address_space(1))) void*)(g), \
    (__attribute__((address_space(3))) void*)(l), 16, 0, 0)

// ---------------------------------------------------------------------------
// MFMA GEMM: 128x128 tile, BK=32, 4 waves (2x2 of 64x64), 16B global_load_lds.
// EPI=0: C bf16.  EPI=1: C fp32.
// EPI=2: blend-scatter RMW into `fused` (fused += w0*attn_m*(acc+bias)).
// EPI=3: scores epilogue: scoresOut[orow*8+beta] = sum_col (acc+bias)*q.
// ---------------------------------------------------------------------------
template <int EPI>
__global__ __launch_bounds__(256) void gemm_mfma(
    const u16* __restrict__ A, const u16* __restrict__ Wt,
    const float* __restrict__ bias, void* __restrict__ Cv,
    int K, int lgIn, int lgOut,
    const float* __restrict__ scores, const float* __restrict__ coef,
    u16* __restrict__ fused, int m,
    const u16* __restrict__ q16, float* __restrict__ scoresOut)
{
    __shared__ u16 As[128 * 32];
    __shared__ u16 Bs[128 * 32];
    __shared__ float attnw[256];     // EPI==2 only
    const int tid = threadIdx.x;
    const int lane = tid & 63;
    const int wid = tid >> 6;
    const int wr = wid >> 1, wc = wid & 1;
    const int row0 = blockIdx.x * 128;
    const int n0 = blockIdx.y * 128;

    const int sr0 = wid * 32 + (lane >> 2);
    const int sr1 = sr0 + 16;
    const int kp = (lane & 3) * 8;
    const u16* aSrc0 = A + mapRow(row0 + sr0, lgIn) * (size_t)K + kp;
    const u16* aSrc1 = A + mapRow(row0 + sr1, lgIn) * (size_t)K + kp;
    const u16* bSrc0 = Wt + (size_t)(n0 + sr0) * K + kp;
    const u16* bSrc1 = Wt + (size_t)(n0 + sr1) * K + kp;
    u16* aDst0 = &As[wid * 1024];
    u16* aDst1 = &As[wid * 1024 + 512];
    u16* bDst0 = &Bs[wid * 1024];
    u16* bDst1 = &Bs[wid * 1024 + 512];

    f32x4 acc[4][4];
#pragma unroll
    for (int mr = 0; mr < 4; ++mr)
#pragma unroll
        for (int nr = 0; nr < 4; ++nr)
            acc[mr][nr] = (f32x4){0.f, 0.f, 0.f, 0.f};

    const int koff = (lane >> 4) * 8;
    const int fr = lane & 15;

    for (int k0 = 0; k0 < K; k0 += 32) {
        GLOAD_LDS16(aSrc0 + k0, aDst0);
        GLOAD_LDS16(aSrc1 + k0, aDst1);
        GLOAD_LDS16(bSrc0 + k0, bDst0);
        GLOAD_LDS16(bSrc1 + k0, bDst1);
        __syncthreads();
        i32x4 af[4], bf[4];
#pragma unroll
        for (int mr = 0; mr < 4; ++mr)
            af[mr] = *(const i32x4*)&As[(wr * 64 + mr * 16 + fr) * 32 + koff];
#pragma unroll
        for (int nr = 0; nr < 4; ++nr)
            bf[nr] = *(const i32x4*)&Bs[(wc * 64 + nr * 16 + fr) * 32 + koff];
#pragma unroll
        for (int mr = 0; mr < 4; ++mr)
#pragma unroll
            for (int nr = 0; nr < 4; ++nr)
                asm volatile("v_mfma_f32_16x16x32_bf16 %0, %1, %2, %0"
                             : "+v"(acc[mr][nr]) : "v"(af[mr]), "v"(bf[nr]));
        __syncthreads();
    }
    asm volatile("s_nop 7\n\ts_nop 7\n\ts_nop 7");

    float bv[4];
#pragma unroll
    for (int nr = 0; nr < 4; ++nr) bv[nr] = bias[n0 + wc * 64 + nr * 16 + fr];
    const int rloc0 = wr * 64 + (lane >> 4) * 4;

    if constexpr (EPI == 3) {
        const int beta = (n0 >> 6) + wc;
#pragma unroll
        for (int mr = 0; mr < 4; ++mr) {
#pragma unroll
            for (int j = 0; j < 4; ++j) {
                const int rloc = rloc0 + mr * 16 + j;
                size_t orow = mapRow(row0 + rloc, lgOut);
                const u16* qrow = q16 + orow * CD + n0 + wc * 64 + fr;
                float p = 0.f;
#pragma unroll
                for (int nr = 0; nr < 4; ++nr)
                    p = fmaf(acc[mr][nr][j] + bv[nr], bf2f(qrow[nr * 16]), p);
                p += __shfl_xor(p, 1, 64);
                p += __shfl_xor(p, 2, 64);
                p += __shfl_xor(p, 4, 64);
                p += __shfl_xor(p, 8, 64);
                if (fr == 0)
                    scoresOut[orow * 8 + beta] = p;
            }
        }
        return;
    }

    if constexpr (EPI == 2) {
        int r = tid >> 1, bi = tid & 1;
        size_t orow = mapRow(row0 + r, lgOut);
        size_t sidx = orow * 8 + (n0 >> 6) + bi;
        float inv_scale = coef[0], w0c = coef[1];
        float s0 = scores[sidx] * inv_scale;
        float s1 = scores[(size_t)CBS * 8 + sidx] * inv_scale;
        float s2 = scores[(size_t)2 * CBS * 8 + sidx] * inv_scale;
        float mx = fmaxf(s0, fmaxf(s1, s2));
        float e0 = __expf(s0 - mx), e1 = __expf(s1 - mx), e2 = __expf(s2 - mx);
        float sel = (m == 0) ? e0 : ((m == 1) ? e1 : e2);
        attnw[tid] = w0c * sel / (e0 + e1 + e2);
        __syncthreads();
    }

#pragma unroll
    for (int mr = 0; mr < 4; ++mr) {
#pragma unroll
        for (int j = 0; j < 4; ++j) {
            const int rloc = rloc0 + mr * 16 + j;
            size_t orow = mapRow(row0 + rloc, lgOut);
            if constexpr (EPI == 2) {
                int b = (int)(orow >> 10), R = (int)(orow & 1023);
                float aw = attnw[rloc * 2 + wc];
                int spBase = ((R & 127) << 3);
                int dpBase = ((R >> 7) << 6);
#pragma unroll
                for (int nr = 0; nr < 4; ++nr) {
                    int cg = n0 + wc * 64 + nr * 16 + fr;
                    float v = acc[mr][nr][j] + bv[nr];
                    size_t off = ((size_t)(b << 10) + spBase + (cg >> 6)) * CD
                               + dpBase + (cg & 63);
                    fused[off] = f2bf(bf2f(fused[off]) + aw * v);
                }
            } else {
#pragma unroll
                for (int nr = 0; nr < 4; ++nr) {
                    float v = acc[mr][nr][j] + bv[nr];
                    int col = n0 + wc * 64 + nr * 16 + fr;
                    if constexpr (EPI == 0)
                        ((u16*)Cv)[orow * CD + col] = f2bf(v);
                    else
                        ((float*)Cv)[orow * CD + col] = v;
                }
            }
        }
    }
}

// flat fp32 -> bf16 conversion (vectorized, n multiple of 4)
__global__ __launch_bounds__(256) void cvt_f32_bf16(
    const float* __restrict__ in, u16* __restrict__ out, int n4)
{
    int i = blockIdx.x * 256 + threadIdx.x;
    if (i < n4) {
        float4 v = ((const float4*)in)[i];
        ((ushort4*)out)[i] = make_ushort4(f2bf(v.x), f2bf(v.y), f2bf(v.z), f2bf(v.w));
    }
}

// W (K x 512 fp32) -> Wt (512 x K bf16), 32x32 LDS tiles. block (32,8).
__global__ void transpose_w(const float* __restrict__ W, u16* __restrict__ Wt, int K)
{
    __shared__ u16 t[32][33];
    int k0 = blockIdx.x * 32, n0 = blockIdx.y * 32;
    int tx = threadIdx.x, ty = threadIdx.y;
#pragma unroll
    for (int i = 0; i < 4; ++i)
        t[ty + i * 8][tx] = f2bf(W[(size_t)(k0 + ty + i * 8) * 512 + n0 + tx]);
    __syncthreads();
#pragma unroll
    for (int i = 0; i < 4; ++i)
        Wt[(size_t)(n0 + ty + i * 8) * K + k0 + tx] = t[tx][ty + i * 8];
}

// five 512x512 transposes in one dispatch (blockIdx.z selects the pair)
struct TP5 { const float* src[5]; u16* dst[5]; };
__global__ void transpose5(TP5 tp)
{
    __shared__ u16 t[32][33];
    const float* W = tp.src[blockIdx.z];
    u16* Wt = tp.dst[blockIdx.z];
    int k0 = blockIdx.x * 32, n0 = blockIdx.y * 32;
    int tx = threadIdx.x, ty = threadIdx.y;
#pragma unroll
    for (int i = 0; i < 4; ++i)
        t[ty + i * 8][tx] = f2bf(W[(size_t)(k0 + ty + i * 8) * 512 + n0 + tx]);
    __syncthreads();
#pragma unroll
    for (int i = 0; i < 4; ++i)
        Wt[(size_t)(n0 + ty + i * 8) * 512 + k0 + tx] = t[tx][ty + i * 8];
}

// Fill pad rows [Lstart, S) of a (B,S,D) bf16 buffer with the fp32 bias row.
__global__ void fill_rows_bf16(u16* __restrict__ dst, const float* __restrict__ bias,
                               int Lstart)
{
    int s = Lstart + blockIdx.x;
    int b = blockIdx.y;
    ushort4* r = (ushort4*)(dst + ((size_t)b * CS + s) * CD);
    int c = threadIdx.x;
    float4 bv = ((const float4*)bias)[c];
    r[c] = make_ushort4(f2bf(bv.x), f2bf(bv.y), f2bf(bv.z), f2bf(bv.w));
}

// Zero pad rows [Lstart, S) of a (B,S,D) bf16 buffer.
__global__ void zero_rows_bf16(u16* __restrict__ dst, int Lstart)
{
    int s = Lstart + blockIdx.x;
    int b = blockIdx.y;
    ushort4* r = (ushort4*)(dst + ((size_t)b * CS + s) * CD);
    r[threadIdx.x] = make_ushort4(0, 0, 0, 0);
}

// Pad-row scores: k pad row == bk (fp32). scores[m][bR][beta] = q[bR]blk . bk|blk
// Covers m0 rows R>=512 (16384 rows) and m1 rows R>=256 (24576 rows).
__global__ __launch_bounds__(256) void pad_scores(
    const u16* __restrict__ q, const float* __restrict__ bk,
    float* __restrict__ scores)
{
    int wave = threadIdx.x >> 6, lane = threadIdx.x & 63;
    int base = blockIdx.x * 32 + wave * 8;
    float4 k1 = ((const float4*)bk)[lane * 2];
    float4 k2 = ((const float4*)bk)[lane * 2 + 1];
#pragma unroll
    for (int t = 0; t < 8; ++t) {
        int id = base + t;
        int m, bR;
        if (id < 16384) { m = 0; bR = ((id >> 9) << 10) + 512 + (id & 511); }
        else {
            unsigned i2 = id - 16384;
            unsigned b = i2 / 768u;
            m = 1; bR = (int)((b << 10) + 256 + (i2 - b * 768u));
        }
        i32x4 qu = *(const i32x4*)(q + (size_t)bR * CD + lane * 8);
        float p = 0.f;
        p = fmaf(bfLO(qu[0]), k1.x, p); p = fmaf(bfHI(qu[0]), k1.y, p);
        p = fmaf(bfLO(qu[1]), k1.z, p); p = fmaf(bfHI(qu[1]), k1.w, p);
        p = fmaf(bfLO(qu[2]), k2.x, p); p = fmaf(bfHI(qu[2]), k2.y, p);
        p = fmaf(bfLO(qu[3]), k2.z, p); p = fmaf(bfHI(qu[3]), k2.w, p);
        p += __shfl_xor(p, 1, 64);
        p += __shfl_xor(p, 2, 64);
        p += __shfl_xor(p, 4, 64);
        if ((lane & 7) == 0)
            scores[(size_t)m * CBS * 8 + (size_t)bR * 8 + (lane >> 3)] = p;
    }
}

#define WREDUCE6(d00,d11,d22,d01,d02,d12) \
    _Pragma("unroll") \
    for (int off = 32; off >= 1; off >>= 1) { \
        d00 += __shfl_xor(d00, off, 64); d11 += __shfl_xor(d11, off, 64); \
        d22 += __shfl_xor(d22, off, 64); d01 += __shfl_xor(d01, off, 64); \
        d02 += __shfl_xor(d02, off, 64); d12 += __shfl_xor(d12, off, 64); }

// Region-aware per-batch stats: pad rows contribute exactly 0, so only load
// the modalities that are real at row s. 4096 chunks x 8 rows, 1024 blocks.
__global__ __launch_bounds__(256) void stats_kernel(
    const u16* __restrict__ feats, float* __restrict__ accum)
{
    int wave = threadIdx.x >> 6, lane = threadIdx.x & 63;
    int chunk = blockIdx.x * 4 + wave;
    int r0 = chunk * 8;
    int b = r0 >> 10, s = r0 & 1023;
    const u16* base = feats + (size_t)r0 * CD + lane * 8;
    float* acc = accum + b * 9;

    if (s >= 512) {                       // audio only: F22
        float a2 = 0;
#pragma unroll
        for (int t = 0; t < 8; ++t) {
            i32x4 u2 = *(const i32x4*)(base + (size_t)t * CD + 2 * CBSD);
            float d22 = 0;
#pragma unroll
            for (int j = 0; j < 4; ++j) {
                float x = bfLO(u2[j]), y = bfHI(u2[j]);
                d22 = fmaf(x, x, d22); d22 = fmaf(y, y, d22);
            }
#pragma unroll
            for (int off = 32; off >= 1; off >>= 1) d22 += __shfl_xor(d22, off, 64);
            a2 += d22;
        }
        if (lane == 0) atomicAdd(acc + 2, a2);
    } else if (s >= 256) {                // text+audio: F00,F22,F02,c02
        float a0 = 0, a2 = 0, a4 = 0, a7 = 0;
#pragma unroll
        for (int t = 0; t < 8; ++t) {
            const u16* f0 = base + (size_t)t * CD;
            i32x4 u0 = *(const i32x4*)f0;
            i32x4 u2 = *(const i32x4*)(f0 + 2 * CBSD);
            float d00 = 0, d22 = 0, d02 = 0;
#pragma unroll
            for (int j = 0; j < 4; ++j) {
                float x0 = bfLO(u0[j]), y0 = bfHI(u0[j]);
                float x2 = bfLO(u2[j]), y2 = bfHI(u2[j]);
                d00 = fmaf(x0, x0, d00); d00 = fmaf(y0, y0, d00);
                d22 = fmaf(x2, x2, d22); d22 = fmaf(y2, y2, d22);
                d02 = fmaf(x0, x2, d02); d02 = fmaf(y0, y2, d02);
            }
#pragma unroll
            for (int off = 32; off >= 1; off >>= 1) {
                d00 += __shfl_xor(d00, off, 64);
                d22 += __shfl_xor(d22, off, 64);
                d02 += __shfl_xor(d02, off, 64);
            }
            float n0 = fmaxf(sqrtf(d00), 1e-12f);
            float n2 = fmaxf(sqrtf(d22), 1e-12f);
            a0 += d00; a2 += d22; a4 += d02; a7 += d02 / (n0 * n2);
        }
        if (lane == 0) {
            atomicAdd(acc + 0, a0); atomicAdd(acc + 2, a2);
            atomicAdd(acc + 4, a4); atomicAdd(acc + 7, a7);
        }
    } else {                              // all three modalities
        float a0 = 0, a1 = 0, a2 = 0, a3 = 0, a4 = 0, a5 = 0, a6 = 0, a7 = 0, a8 = 0;
#pragma unroll
        for (int t = 0; t < 8; ++t) {
            const u16* f0 = base + (size_t)t * CD;
            i32x4 u0 = *(const i32x4*)f0;
            i32x4 u1 = *(const i32x4*)(f0 + CBSD);
            i32x4 u2 = *(const i32x4*)(f0 + 2 * CBSD);
            float d00 = 0, d11 = 0, d22 = 0, d01 = 0, d02 = 0, d12 = 0;
#pragma unroll
            for (int j = 0; j < 4; ++j) {
                float x0 = bfLO(u0[j]), y0 = bfHI(u0[j]);
                float x1 = bfLO(u1[j]), y1 = bfHI(u1[j]);
                float x2 = bfLO(u2[j]), y2 = bfHI(u2[j]);
                d00 = fmaf(x0, x0, d00); d00 = fmaf(y0, y0, d00);
                d11 = fmaf(x1, x1, d11); d11 = fmaf(y1, y1, d11);
                d22 = fmaf(x2, x2, d22); d22 = fmaf(y2, y2, d22);
                d01 = fmaf(x0, x1, d01); d01 = fmaf(y0, y1, d01);
                d02 = fmaf(x0, x2, d02); d02 = fmaf(y0, y2, d02);
                d12 = fmaf(x1, x2, d12); d12 = fmaf(y1, y2, d12);
            }
            WREDUCE6(d00, d11, d22, d01, d02, d12)
            float n0 = fmaxf(sqrtf(d00), 1e-12f);
            float n1 = fmaxf(sqrtf(d11), 1e-12f);
            float n2 = fmaxf(sqrtf(d22), 1e-12f);
            a0 += d00; a1 += d11; a2 += d22; a3 += d01; a4 += d02; a5 += d12;
            a6 += d01 / (n0 * n1); a7 += d02 / (n0 * n2); a8 += d12 / (n1 * n2);
        }
        if (lane == 0) {
            atomicAdd(acc + 0, a0); atomicAdd(acc + 1, a1); atomicAdd(acc + 2, a2);
            atomicAdd(acc + 3, a3); atomicAdd(acc + 4, a4); atomicAdd(acc + 5, a5);
            atomicAdd(acc + 6, a6); atomicAdd(acc + 7, a7); atomicAdd(acc + 8, a8);
        }
    }
}

// coef[0]=1/(8|t|), coef[1]=w0, coef[4+b*3+i] = w1*aw[b,i] + w2*cw[b,i].
__global__ void finalize_kernel(const float* __restrict__ accum,
                                const float* __restrict__ temp,
                                const float* __restrict__ attw,
                                const float* __restrict__ rolew,
                                float* __restrict__ coef)
{
    float t_abs = fabsf(temp[0]);
    float x0 = attw[0], x1 = attw[1], x2 = attw[2];
    float mx = fmaxf(x0, fmaxf(x1, x2));
    float e0 = expf(x0 - mx), e1 = expf(x1 - mx), e2 = expf(x2 - mx);
    float inv = 1.0f / (e0 + e1 + e2);
    float w0 = e0 * inv, w1 = e1 * inv, w2 = e2 * inv;
    int b = threadIdx.x;
    if (b == 0) { coef[0] = 1.0f / (8.0f * t_abs); coef[1] = w0; }
    if (b < CB) {
        const float* A = accum + b * 9;
        float Fm[3][3];
        Fm[0][0] = A[0]; Fm[1][1] = A[1]; Fm[2][2] = A[2];
        Fm[0][1] = Fm[1][0] = A[3];
        Fm[0][2] = Fm[2][0] = A[4];
        Fm[1][2] = Fm[2][1] = A[5];
        float cn[3] = {A[6], A[7], A[8]};
        float eij[3];
#pragma unroll
        for (int p = 0; p < 3; ++p) {
            float c = cn[p] * (1.0f / 1024.0f);
            c = fminf(fmaxf(c, -1.0f + 1e-7f), 1.0f - 1e-7f);
            eij[p] = expf(-acosf(c) / t_abs);
        }
        float r0 = rolew[0], r1 = rolew[1], r2 = rolew[2];
        float as0 = r1 * eij[0] + r2 * eij[1];
        float as1 = r0 * eij[0] + r2 * eij[2];
        float as2 = r0 * eij[1] + r1 * eij[2];
        float amx = fmaxf(as0, fmaxf(as1, as2));
        float ea0 = expf(as0 - amx), ea1 = expf(as1 - amx), ea2 = expf(as2 - amx);
        float ainv = 1.0f / (ea0 + ea1 + ea2);
        float awv[3] = {ea0 * ainv, ea1 * ainv, ea2 * ainv};
        const float CA = 0.70710678118654752440f;   // cos(pi/4)
        const float C2 = 6.123233995736766e-17f;    // cos(pi/2)
        float vols[3];
#pragma unroll
        for (int i = 0; i < 3; ++i) {
            int j1 = (i + 1) % 3, j2 = (i + 2) % 3;
            float G00 = Fm[i][i];
            float G11 = CA * CA * (Fm[i][i] + 2.0f * Fm[i][j1] + Fm[j1][j1]);
            float G22 = C2 * C2 * Fm[i][i] + 2.0f * C2 * Fm[i][j2] + Fm[j2][j2];
            float G01 = CA * (Fm[i][i] + Fm[i][j1]);
            float G02 = C2 * Fm[i][i] + Fm[i][j2];
            float G12 = CA * (C2 * (Fm[i][i] + Fm[i][j1]) + Fm[i][j2] + Fm[j1][j2]);
            vols[i] = (4.0f / 9.0f) * ((G00 + G11 + G22) - (G01 + G02 + G12));
        }
        float vmx = fmaxf(vols[0], fmaxf(vols[1], vols[2]));
        float ev0 = expf((vols[0] - vmx) / t_abs);
        float ev1 = expf((vols[1] - vmx) / t_abs);
        float ev2 = expf((vols[2] - vmx) / t_abs);
        float vinv = 1.0f / (ev0 + ev1 + ev2);
        coef[4 + b * 3 + 0] = w1 * awv[0] + w2 * (ev0 * vinv);
        coef[4 + b * 3 + 1] = w1 * awv[1] + w2 * (ev1 * vinv);
        coef[4 + b * 3 + 2] = w1 * awv[2] + w2 * (ev2 * vinv);
    }
}

// fused init: g-weighted feats + pad-row attention terms (pad V row == bias).
__global__ __launch_bounds__(256) void blend_init(
    const u16* __restrict__ feats, const float* __restrict__ scores,
    const float* __restrict__ coef, const float* __restrict__ bv,
    u16* __restrict__ fused)
{
    int bR = blockIdx.x;
    int b = bR >> 10, R = bR & 1023;
    float inv_scale = coef[0], w0c = coef[1];
    float g0 = coef[4 + b * 3 + 0];
    float g1 = coef[4 + b * 3 + 1];
    float g2 = coef[4 + b * 3 + 2];
    int h = R >> 7;
    int spBase = (R & 127) << 3;
#pragma unroll
    for (int it = 0; it < 2; ++it) {
        int c = (it << 8) + threadIdx.x;
        int beta = c >> 6, e = c & 63;
        size_t off = ((size_t)(b << 10) + spBase + beta) * CD + (h << 6) + e;
        float val = g0 * bf2f(feats[off]) + g1 * bf2f(feats[off + CBSD])
                  + g2 * bf2f(feats[off + 2 * CBSD]);
        if (R >= 256) {   // pad-row attn terms exist only for R >= 256
            size_t sidx = (size_t)bR * 8 + beta;
            float s0 = scores[sidx] * inv_scale;
            float s1 = scores[(size_t)CBS * 8 + sidx] * inv_scale;
            float s2 = scores[(size_t)2 * CBS * 8 + sidx] * inv_scale;
            float mxs = fmaxf(s0, fmaxf(s1, s2));
            float ex0 = __expf(s0 - mxs), ex1 = __expf(s1 - mxs), ex2 = __expf(s2 - mxs);
            float den = ex0 + ex1 + ex2;
            float bvc = bv[c];
            float t = ex1;                       // m1 pad (image, L=256)
            if (R >= 512) t += ex0;              // m0 pad (text, L=512)
            val += w0c * (t / den) * bvc;
        }
        fused[off] = f2bf(val);
    }
}

extern "C" void kernel_launch(void* const* d_in, const int* in_sizes, int n_in,
                              void* d_out, int out_size, void* d_ws, size_t ws_size,
                              hipStream_t stream)
{
    const float* text  = (const float*)d_in[0];
    const float* image = (const float*)d_in[1];
    const float* audio = (const float*)d_in[2];
    const float* W0 = (const float*)d_in[3];  const float* b0 = (const float*)d_in[4];
    const float* W1 = (const float*)d_in[5];  const float* b1 = (const float*)d_in[6];
    const float* W2 = (const float*)d_in[7];  const float* b2 = (const float*)d_in[8];
    const float* Wq = (const float*)d_in[9];  const float* bq = (const float*)d_in[10];
    const float* Wk = (const float*)d_in[11]; const float* bk = (const float*)d_in[12];
    const float* Wv = (const float*)d_in[13]; const float* bv = (const float*)d_in[14];
    const float* Wo = (const float*)d_in[15]; const float* bo = (const float*)d_in[16];
    const float* temp  = (const float*)d_in[17];
    const float* attw  = (const float*)d_in[18];
    const float* rolew = (const float*)d_in[19];

    // ws layout (~171.4 MB, same as passing R5)
    u16* feats  = (u16*)d_ws;                 // 3*CBSD bf16
    u16* kv     = feats + 3 * CBSD;           // CBSD bf16 (cvt staging)
    u16* fused  = kv + CBSD;                  // CBSD bf16
    float* scores = (float*)(fused + CBSD);   // 3*CBS*8 f32
    float* accum  = scores + (size_t)3 * CBS * 8;  // 320 f32
    float* coef   = accum + 320;              // 128 f32
    u16* wot      = (u16*)(coef + 128);       // 512*512 bf16 (NOT in d_out)

    // d_out tail as scratch
    u16* q = (u16*)d_out;                     // CBSD bf16; dead before final GEMM
    u16* wpool = q + CBSD;
    u16* w0t = wpool;                         // 512*768
    u16* w1t = w0t + 512 * 768;               // 512*1024
    u16* w2t = w1t + 512 * 1024;              // 512*512
    u16* wqt = w2t + 512 * 512;
    u16* wkt = wqt + 512 * 512;
    u16* wvt = wkt + 512 * 512;

    const dim3 blk(256);
    const dim3 tblk(32, 8);
    const int Lm[3] = {512, 256, 1024};
    const int lg[3] = {9, 8, 10};
    const float* bm[3] = {b0, b1, b2};
    const float* xm[3] = {text, image, audio};
    u16* wmt[3] = {w0t, w1t, w2t};
    const int Km[3] = {768, 1024, 512};

    zero_rows_bf16<<<dim3(512, CB), dim3(128), 0, stream>>>(feats, 512);
    zero_rows_bf16<<<dim3(768, CB), dim3(128), 0, stream>>>(feats + CBSD, 256);
    hipMemsetAsync(accum, 0, 320 * sizeof(float), stream);

    // weight transposes
    transpose_w<<<dim3(24, 16), tblk, 0, stream>>>(W0, w0t, 768);
    transpose_w<<<dim3(32, 16), tblk, 0, stream>>>(W1, w1t, 1024);
    TP5 tp;
    tp.src[0] = W2; tp.dst[0] = w2t;
    tp.src[1] = Wq; tp.dst[1] = wqt;
    tp.src[2] = Wk; tp.dst[2] = wkt;
    tp.src[3] = Wv; tp.dst[3] = wvt;
    tp.src[4] = Wo; tp.dst[4] = wot;
    transpose5<<<dim3(16, 16, 5), tblk, 0, stream>>>(tp);

    // input projections
    for (int m = 0; m < 3; ++m) {
        int n = CB * Lm[m] * Km[m];
        cvt_f32_bf16<<<dim3(n / 1024), blk, 0, stream>>>(xm[m], kv, n / 4);
        gemm_mfma<0><<<dim3(CB * Lm[m] / 128, 4), blk, 0, stream>>>(
            kv, wmt[m], bm[m], feats + (size_t)m * CBSD, Km[m], 10, lg[m],
            nullptr, nullptr, nullptr, 0, nullptr, nullptr);
    }

    // Q projection + pad fill (audio-K scores at R>=512 need q = bq rows)
    gemm_mfma<0><<<dim3(128, 4), blk, 0, stream>>>(
        feats, wqt, bq, q, 512, 9, 9, nullptr, nullptr, nullptr, 0, nullptr, nullptr);
    fill_rows_bf16<<<dim3(512, CB), dim3(128), 0, stream>>>(q, bq, 512);

    // angular + Cayley stats
    stats_kernel<<<dim3(1024), blk, 0, stream>>>(feats, accum);
    finalize_kernel<<<dim3(1), dim3(64), 0, stream>>>(accum, temp, attw, rolew, coef);

    // K GEMMs with fused scores epilogue (real rows); pads via pad_scores
    for (int m = 0; m < 3; ++m) {
        gemm_mfma<3><<<dim3(CB * Lm[m] / 128, 4), blk, 0, stream>>>(
            feats + (size_t)m * CBSD, wkt, bk, nullptr, 512, lg[m], lg[m],
            nullptr, nullptr, nullptr, 0, q, scores + (size_t)m * CBS * 8);
    }
    pad_scores<<<dim3(1280), blk, 0, stream>>>(q, bk, scores);

    // fused init (g-feats + pad-row attn terms), then V GEMMs scatter-blend
    blend_init<<<dim3(CBS), blk, 0, stream>>>(feats, scores, coef, bv, fused);
    for (int m = 0; m < 3; ++m) {
        gemm_mfma<2><<<dim3(CB * Lm[m] / 128, 4), blk, 0, stream>>>(
            feats + (size_t)m * CBSD, wvt, bv, nullptr, 512, lg[m], lg[m],
            scores, coef, fused, m, nullptr, nullptr);
    }

    // output projection
    gemm_mfma<1><<<dim3(256, 4), blk, 0, stream>>>(
        fused, wot, bo, (float*)d_out, 512, 10, 10,
        nullptr, nullptr, nullptr, 0, nullptr, nullptr);
}